// Round 1
// baseline (1294.549 us; speedup 1.0000x reference)
//
#include <hip/hip_runtime.h>
#include <math.h>

#define B_ 2
#define S_ 2048
#define DM_ 2048
#define H_ 16
#define KVH_ 4
#define HD_ 128
#define NC_ 16
#define CHK_ 128
#define EPS_ 1e-6f

// ------------------------------------------------------------------ RoPE tables
// cos/sin[s][j], j<64 ; cos[s][j+64] == cos[s][j] in the reference (concat of freqs)
__global__ __launch_bounds__(256) void rope_tables_k(float* __restrict__ cost,
                                                     float* __restrict__ sint) {
    int idx = blockIdx.x * 256 + threadIdx.x;      // S_*64 exact
    int j = idx & 63;
    int s = idx >> 6;
    float inv_freq = powf(10000.0f, -(float)(2 * j) / 128.0f);
    float f = (float)s * inv_freq;
    cost[idx] = cosf(f);
    sint[idx] = sinf(f);
}

// ------------------------------------------------------------------ fp32 GEMM
// Y[m, n] = sum_k A[m,k] * W[n,k]   (torch Linear semantics, W row-major [N][K])
// Weight chosen per n-block among {W0,W1,W2} with column boundaries nend0/nend1
// (lets one launch compute the concatenated q|k|v projection).
#define GBM 128
#define GBN 128
#define GBK 16
__global__ __launch_bounds__(256) void gemm_xwt_k(
    const float* __restrict__ A, const float* __restrict__ W0,
    const float* __restrict__ W1, const float* __restrict__ W2,
    float* __restrict__ Y, int K, int ldY, int nend0, int nend1)
{
    // transposed LDS tiles: As[k][m] — staging writes are 2-way bank aliasing (free),
    // compute reads are aligned b128 (row stride 132*4B = 528, 16B aligned)
    __shared__ __attribute__((aligned(16))) float As[GBK][GBM + 4];
    __shared__ __attribute__((aligned(16))) float Bs[GBK][GBN + 4];
    const int n0 = blockIdx.x * GBN;
    const int m0 = blockIdx.y * GBM;
    const float* W;
    int nw;
    if (n0 < nend0)      { W = W0; nw = n0; }
    else if (n0 < nend1) { W = W1; nw = n0 - nend0; }
    else                 { W = W2; nw = n0 - nend1; }
    const int tid = threadIdx.x;
    const int tx = tid & 15, ty = tid >> 4;
    const int r0 = tid >> 2;      // 0..63 (row), second half at r0+64
    const int c4 = tid & 3;       // float4 slot within the 16-wide K slab

    float acc[8][8];
#pragma unroll
    for (int i = 0; i < 8; i++)
#pragma unroll
        for (int j = 0; j < 8; j++) acc[i][j] = 0.f;

    for (int k0 = 0; k0 < K; k0 += GBK) {
        float4 av0 = *(const float4*)(A + (size_t)(m0 + r0) * K + k0 + c4 * 4);
        float4 av1 = *(const float4*)(A + (size_t)(m0 + r0 + 64) * K + k0 + c4 * 4);
        float4 bv0 = *(const float4*)(W + (size_t)(nw + r0) * K + k0 + c4 * 4);
        float4 bv1 = *(const float4*)(W + (size_t)(nw + r0 + 64) * K + k0 + c4 * 4);
        __syncthreads();   // previous iteration's LDS reads complete
        As[c4 * 4 + 0][r0] = av0.x; As[c4 * 4 + 1][r0] = av0.y;
        As[c4 * 4 + 2][r0] = av0.z; As[c4 * 4 + 3][r0] = av0.w;
        As[c4 * 4 + 0][r0 + 64] = av1.x; As[c4 * 4 + 1][r0 + 64] = av1.y;
        As[c4 * 4 + 2][r0 + 64] = av1.z; As[c4 * 4 + 3][r0 + 64] = av1.w;
        Bs[c4 * 4 + 0][r0] = bv0.x; Bs[c4 * 4 + 1][r0] = bv0.y;
        Bs[c4 * 4 + 2][r0] = bv0.z; Bs[c4 * 4 + 3][r0] = bv0.w;
        Bs[c4 * 4 + 0][r0 + 64] = bv1.x; Bs[c4 * 4 + 1][r0 + 64] = bv1.y;
        Bs[c4 * 4 + 2][r0 + 64] = bv1.z; Bs[c4 * 4 + 3][r0 + 64] = bv1.w;
        __syncthreads();
#pragma unroll
        for (int kk = 0; kk < GBK; kk++) {
            float a[8], b[8];
            *(float4*)&a[0] = *(const float4*)&As[kk][ty * 8];
            *(float4*)&a[4] = *(const float4*)&As[kk][ty * 8 + 4];
            *(float4*)&b[0] = *(const float4*)&Bs[kk][tx * 8];
            *(float4*)&b[4] = *(const float4*)&Bs[kk][tx * 8 + 4];
#pragma unroll
            for (int i = 0; i < 8; i++)
#pragma unroll
                for (int j = 0; j < 8; j++)
                    acc[i][j] = fmaf(a[i], b[j], acc[i][j]);
        }
    }
#pragma unroll
    for (int i = 0; i < 8; i++) {
        float* yp = Y + (size_t)(m0 + ty * 8 + i) * ldY + n0 + tx * 8;
        *(float4*)yp       = make_float4(acc[i][0], acc[i][1], acc[i][2], acc[i][3]);
        *(float4*)(yp + 4) = make_float4(acc[i][4], acc[i][5], acc[i][6], acc[i][7]);
    }
}

// ------------------------------------------------------------------ RoPE + elu(+1) for q,k
// qkv_raw row layout: [q 0..2047 | k 2048..2559 | v 2560..3071]
__global__ __launch_bounds__(256) void rope_feat_k(
    const float* __restrict__ qkv, const float* __restrict__ cost,
    const float* __restrict__ sint, float* __restrict__ qf, float* __restrict__ kf)
{
    int idx = blockIdx.x * 256 + threadIdx.x;  // B_*S_*20*64 exact
    int j = idx & 63;
    int t = idx >> 6;
    int hh = t % 20;
    int t2 = t / 20;
    int s = t2 % S_;
    int b = t2 / S_;
    const float* row = qkv + (size_t)(b * S_ + s) * 3072;
    int col;
    float* outp;
    if (hh < H_) {
        col = hh * HD_;
        outp = qf + ((size_t)(b * H_ + hh) * S_ + s) * HD_;
    } else {
        int kv = hh - H_;
        col = 2048 + kv * HD_;
        outp = kf + ((size_t)(b * KVH_ + kv) * S_ + s) * HD_;
    }
    float x1 = row[col + j];
    float x2 = row[col + j + 64];
    float cs = cost[s * 64 + j];
    float sn = sint[s * 64 + j];
    float o1 = x1 * cs - x2 * sn;   // d<64 : x*cos - x[d+64]*sin
    float o2 = x2 * cs + x1 * sn;   // d>=64: x*cos + x[d-64]*sin
    o1 = o1 > 0.f ? o1 + 1.f : expf(o1);   // elu(x)+1
    o2 = o2 > 0.f ? o2 + 1.f : expf(o2);
    outp[j] = o1;
    outp[j + 64] = o2;
}

// ------------------------------------------------------------------ V layout transform
__global__ __launch_bounds__(256) void copy_v_k(const float* __restrict__ qkv,
                                                float* __restrict__ v)
{
    int idx = blockIdx.x * 256 + threadIdx.x;  // B_*S_*KVH_*32 float4s exact
    int d4 = idx & 31;
    int t = idx >> 5;
    int kv = t & 3;
    int t2 = t >> 2;
    int s = t2 % S_;
    int b = t2 / S_;
    float4 val = *(const float4*)(qkv + (size_t)(b * S_ + s) * 3072 + 2560 + kv * HD_ + d4 * 4);
    *(float4*)(v + ((size_t)(b * KVH_ + kv) * S_ + s) * HD_ + d4 * 4) = val;
}

// ------------------------------------------------------------------ per-chunk KV summaries
// kvc[bkv,c][e][d] = sum_j kf[j][e]*v[j][d] ; zc[bkv,c][e] = sum_j kf[j][e]
__global__ __launch_bounds__(256) void chunk_kv_k(
    const float* __restrict__ kf, const float* __restrict__ vv,
    float* __restrict__ kvc, float* __restrict__ zc)
{
    int bx = blockIdx.x;             // (b*KVH+kv)*NC + c
    int c = bx % NC_;
    int bkv = bx / NC_;
    const float* kp = kf + ((size_t)bkv * S_ + c * CHK_) * HD_;
    const float* vp = vv + ((size_t)bkv * S_ + c * CHK_) * HD_;
    __shared__ __attribute__((aligned(16))) float ks[CHK_][HD_ + 4];
    __shared__ __attribute__((aligned(16))) float vs[CHK_][HD_ + 4];
    int tid = threadIdx.x, tx = tid & 15, ty = tid >> 4;
#pragma unroll
    for (int it = 0; it < 16; it++) {
        int idx = it * 256 + tid;          // f4 over 128x32
        int r = idx >> 5, c4 = idx & 31;
        *(float4*)&ks[r][c4 * 4] = *(const float4*)(kp + (size_t)r * HD_ + c4 * 4);
        *(float4*)&vs[r][c4 * 4] = *(const float4*)(vp + (size_t)r * HD_ + c4 * 4);
    }
    __syncthreads();
    float acc[8][8];
#pragma unroll
    for (int i = 0; i < 8; i++)
#pragma unroll
        for (int j = 0; j < 8; j++) acc[i][j] = 0.f;
    for (int j = 0; j < CHK_; j++) {
        float a[8], b[8];
        *(float4*)&a[0] = *(const float4*)&ks[j][ty * 8];
        *(float4*)&a[4] = *(const float4*)&ks[j][ty * 8 + 4];
        *(float4*)&b[0] = *(const float4*)&vs[j][tx * 8];
        *(float4*)&b[4] = *(const float4*)&vs[j][tx * 8 + 4];
#pragma unroll
        for (int i = 0; i < 8; i++)
#pragma unroll
            for (int jj = 0; jj < 8; jj++)
                acc[i][jj] = fmaf(a[i], b[jj], acc[i][jj]);
    }
    float* outp = kvc + (size_t)bx * (HD_ * HD_);
#pragma unroll
    for (int i = 0; i < 8; i++) {
        float* op = outp + (size_t)(ty * 8 + i) * HD_ + tx * 8;
        *(float4*)op       = make_float4(acc[i][0], acc[i][1], acc[i][2], acc[i][3]);
        *(float4*)(op + 4) = make_float4(acc[i][4], acc[i][5], acc[i][6], acc[i][7]);
    }
    if (tid < CHK_) {
        float z = 0.f;
        for (int j = 0; j < CHK_; j++) z += ks[j][tid];
        zc[(size_t)bx * HD_ + tid] = z;
    }
}

// ------------------------------------------------------------------ exclusive chunk scan (in place)
__global__ __launch_bounds__(256) void chunk_scan_k(float* __restrict__ kvc,
                                                    float* __restrict__ zc)
{
    int bkv = blockIdx.x;   // 8
    float* base = kvc + (size_t)bkv * NC_ * HD_ * HD_;
    float* zbase = zc + (size_t)bkv * NC_ * HD_;
    int tid = threadIdx.x;
    float acc[64];
#pragma unroll
    for (int i = 0; i < 64; i++) acc[i] = 0.f;
    float zacc = 0.f;
    for (int c = 0; c < NC_; c++) {
        float* p = base + (size_t)c * HD_ * HD_;
#pragma unroll
        for (int i = 0; i < 64; i++) {
            float cur = p[i * 256 + tid];
            p[i * 256 + tid] = acc[i];
            acc[i] += cur;
        }
        if (tid < CHK_) {
            float* zp = zbase + c * HD_ + tid;
            float zcur = *zp;
            *zp = zacc;
            zacc += zcur;
        }
    }
}

// ------------------------------------------------------------------ per-chunk output
// O = (tril(Q K^T) V + Q Sprefix) / (rowsum(tril(Q K^T)) + Q z_prefix + eps)
__global__ __launch_bounds__(256, 1) void chunk_out_k(
    const float* __restrict__ qf, const float* __restrict__ kf,
    const float* __restrict__ vv, const float* __restrict__ kvpre,
    const float* __restrict__ zpre, float* __restrict__ attn)
{
    int bx = blockIdx.x;                // ((b*H+h)*NC)+c, 512 blocks
    int c = bx & 15;
    int h = (bx >> 4) & 15;
    int b = bx >> 8;
    int kv = h >> 2;                    // GQA group
    int bkvc = (b * KVH_ + kv) * NC_ + c;
    const float* qp = qf + ((size_t)(b * H_ + h) * S_ + c * CHK_) * HD_;
    const float* kp = kf + ((size_t)(b * KVH_ + kv) * S_ + c * CHK_) * HD_;
    const float* vp = vv + ((size_t)(b * KVH_ + kv) * S_ + c * CHK_) * HD_;
    const float* sp = kvpre + (size_t)bkvc * HD_ * HD_;
    const float* zp = zpre + (size_t)bkvc * HD_;

    // LDS: Qt[d][i] (transposed), KtA = Kt[d][j] then At[j][i], Vs stream buffer
    __shared__ __attribute__((aligned(16))) float smem[38272];
    float* Qt    = smem;            // [128][132]
    float* KtA   = smem + 16896;    // [128][132]
    float* Vs    = smem + 33792;    // [32][132]
    float* den_s = smem + 38016;    // [128]
    float* zs    = smem + 38144;    // [128]

    int tid = threadIdx.x, tx = tid & 15, ty = tid >> 4;

    // stage Q,K transposed (writes: 2-way bank aliasing = free)
#pragma unroll
    for (int it = 0; it < 16; it++) {
        int idx = it * 256 + tid;
        int r = idx >> 5, c4 = idx & 31;
        float4 a = *(const float4*)(qp + (size_t)r * HD_ + c4 * 4);
        float4 kq = *(const float4*)(kp + (size_t)r * HD_ + c4 * 4);
        Qt[(c4 * 4 + 0) * 132 + r] = a.x;  Qt[(c4 * 4 + 1) * 132 + r] = a.y;
        Qt[(c4 * 4 + 2) * 132 + r] = a.z;  Qt[(c4 * 4 + 3) * 132 + r] = a.w;
        KtA[(c4 * 4 + 0) * 132 + r] = kq.x; KtA[(c4 * 4 + 1) * 132 + r] = kq.y;
        KtA[(c4 * 4 + 2) * 132 + r] = kq.z; KtA[(c4 * 4 + 3) * 132 + r] = kq.w;
    }
    if (tid < CHK_) zs[tid] = zp[tid];
    __syncthreads();

    // GEMM1: scores A[i][j] = sum_d Q[i][d] K[j][d]
    float acc1[8][8];
#pragma unroll
    for (int i = 0; i < 8; i++)
#pragma unroll
        for (int j = 0; j < 8; j++) acc1[i][j] = 0.f;
    for (int d = 0; d < HD_; d++) {
        float a[8], bb[8];
        *(float4*)&a[0]  = *(const float4*)&Qt[d * 132 + ty * 8];
        *(float4*)&a[4]  = *(const float4*)&Qt[d * 132 + ty * 8 + 4];
        *(float4*)&bb[0] = *(const float4*)&KtA[d * 132 + tx * 8];
        *(float4*)&bb[4] = *(const float4*)&KtA[d * 132 + tx * 8 + 4];
#pragma unroll
        for (int i = 0; i < 8; i++)
#pragma unroll
            for (int j = 0; j < 8; j++)
                acc1[i][j] = fmaf(a[i], bb[j], acc1[i][j]);
    }
    __syncthreads();   // all Kt reads done before overwriting as At

    // causal mask, rowsums (-> den), store At[j][i]
    float rs[8];
#pragma unroll
    for (int i = 0; i < 8; i++) rs[i] = 0.f;
#pragma unroll
    for (int j = 0; j < 8; j++) {
        int gj = tx * 8 + j;
        float e0 = (gj <= ty * 8 + 0) ? acc1[0][j] : 0.f; rs[0] += e0;
        float e1 = (gj <= ty * 8 + 1) ? acc1[1][j] : 0.f; rs[1] += e1;
        float e2 = (gj <= ty * 8 + 2) ? acc1[2][j] : 0.f; rs[2] += e2;
        float e3 = (gj <= ty * 8 + 3) ? acc1[3][j] : 0.f; rs[3] += e3;
        float e4 = (gj <= ty * 8 + 4) ? acc1[4][j] : 0.f; rs[4] += e4;
        float e5 = (gj <= ty * 8 + 5) ? acc1[5][j] : 0.f; rs[5] += e5;
        float e6 = (gj <= ty * 8 + 6) ? acc1[6][j] : 0.f; rs[6] += e6;
        float e7 = (gj <= ty * 8 + 7) ? acc1[7][j] : 0.f; rs[7] += e7;
        *(float4*)&KtA[gj * 132 + ty * 8]     = make_float4(e0, e1, e2, e3);
        *(float4*)&KtA[gj * 132 + ty * 8 + 4] = make_float4(e4, e5, e6, e7);
    }
#pragma unroll
    for (int m = 1; m < 16; m <<= 1) {
#pragma unroll
        for (int i = 0; i < 8; i++) rs[i] += __shfl_xor(rs[i], m, 64);
    }
    if (tx == 0) {
#pragma unroll
        for (int i = 0; i < 8; i++) den_s[ty * 8 + i] = rs[i];
    }
    __syncthreads();
    if (tid < CHK_) {        // den += q_i . z_prefix  (+eps)
        float d2 = 0.f;
        for (int e = 0; e < HD_; e++) d2 = fmaf(Qt[e * 132 + tid], zs[e], d2);
        den_s[tid] += d2 + EPS_;
    }

    // GEMM2 (At*V) + GEMM3 (Q*Sprefix), V/Sp streamed in 32-row slabs
    float acc2[8][8];
#pragma unroll
    for (int i = 0; i < 8; i++)
#pragma unroll
        for (int j = 0; j < 8; j++) acc2[i][j] = 0.f;
    for (int jt = 0; jt < 4; jt++) {
        float4 vld[4];
#pragma unroll
        for (int it = 0; it < 4; it++) {
            int idx = it * 256 + tid;
            int r = idx >> 5, c4 = idx & 31;
            vld[it] = *(const float4*)(vp + (size_t)(jt * 32 + r) * HD_ + c4 * 4);
        }
        __syncthreads();
#pragma unroll
        for (int it = 0; it < 4; it++) {
            int idx = it * 256 + tid;
            int r = idx >> 5, c4 = idx & 31;
            *(float4*)&Vs[r * 132 + c4 * 4] = vld[it];
        }
        __syncthreads();
        for (int j = 0; j < 32; j++) {
            int gj = jt * 32 + j;
            float a[8], bb[8];
            *(float4*)&a[0]  = *(const float4*)&KtA[gj * 132 + ty * 8];
            *(float4*)&a[4]  = *(const float4*)&KtA[gj * 132 + ty * 8 + 4];
            *(float4*)&bb[0] = *(const float4*)&Vs[j * 132 + tx * 8];
            *(float4*)&bb[4] = *(const float4*)&Vs[j * 132 + tx * 8 + 4];
#pragma unroll
            for (int i = 0; i < 8; i++)
#pragma unroll
                for (int jj = 0; jj < 8; jj++)
                    acc2[i][jj] = fmaf(a[i], bb[jj], acc2[i][jj]);
        }
    }
    for (int et = 0; et < 4; et++) {
        float4 vld[4];
#pragma unroll
        for (int it = 0; it < 4; it++) {
            int idx = it * 256 + tid;
            int r = idx >> 5, c4 = idx & 31;
            vld[it] = *(const float4*)(sp + (size_t)(et * 32 + r) * HD_ + c4 * 4);
        }
        __syncthreads();
#pragma unroll
        for (int it = 0; it < 4; it++) {
            int idx = it * 256 + tid;
            int r = idx >> 5, c4 = idx & 31;
            *(float4*)&Vs[r * 132 + c4 * 4] = vld[it];
        }
        __syncthreads();
        for (int e = 0; e < 32; e++) {
            int ge = et * 32 + e;
            float a[8], bb[8];
            *(float4*)&a[0]  = *(const float4*)&Qt[ge * 132 + ty * 8];
            *(float4*)&a[4]  = *(const float4*)&Qt[ge * 132 + ty * 8 + 4];
            *(float4*)&bb[0] = *(const float4*)&Vs[e * 132 + tx * 8];
            *(float4*)&bb[4] = *(const float4*)&Vs[e * 132 + tx * 8 + 4];
#pragma unroll
            for (int i = 0; i < 8; i++)
#pragma unroll
                for (int jj = 0; jj < 8; jj++)
                    acc2[i][jj] = fmaf(a[i], bb[jj], acc2[i][jj]);
        }
    }

    int s0 = c * CHK_;
#pragma unroll
    for (int i = 0; i < 8; i++) {
        int gi = ty * 8 + i;
        float inv = 1.0f / den_s[gi];   // eps already included
        float* op = attn + (size_t)(b * S_ + s0 + gi) * 2048 + h * HD_ + tx * 8;
        *(float4*)op = make_float4(acc2[i][0] * inv, acc2[i][1] * inv,
                                   acc2[i][2] * inv, acc2[i][3] * inv);
        *(float4*)(op + 4) = make_float4(acc2[i][4] * inv, acc2[i][5] * inv,
                                         acc2[i][6] * inv, acc2[i][7] * inv);
    }
}

// ------------------------------------------------------------------ launch
extern "C" void kernel_launch(void* const* d_in, const int* in_sizes, int n_in,
                              void* d_out, int out_size, void* d_ws, size_t ws_size,
                              hipStream_t stream)
{
    (void)in_sizes; (void)n_in; (void)out_size; (void)ws_size;
    const float* x  = (const float*)d_in[0];
    const float* Wq = (const float*)d_in[1];
    const float* Wk = (const float*)d_in[2];
    const float* Wv = (const float*)d_in[3];
    const float* Wo = (const float*)d_in[4];
    float* out = (float*)d_out;
    float* ws  = (float*)d_ws;

    // ws layout (floats); total 27,541,504 floats = 110.2 MB
    float* qkv  = ws;                 // [4096][3072] (reused as attn [4096][2048] later)
    float* qf   = ws + 12582912;      // [B][H][S][D]
    float* kf   = ws + 20971520;      // [B][KVH][S][D]
    float* vv   = ws + 23068672;      // [B][KVH][S][D]
    float* kvc  = ws + 25165824;      // [B*KVH][NC][D][D]
    float* zc   = ws + 27262976;      // [B*KVH][NC][D]
    float* cost = ws + 27279360;      // [S][64]
    float* sint = ws + 27410432;      // [S][64]
    float* attn = qkv;                // alias: qkv_raw dead after rope_feat/copy_v

    rope_tables_k<<<512, 256, 0, stream>>>(cost, sint);
    // QKV projection: M=4096, N=3072 (q|k|v), K=2048
    gemm_xwt_k<<<dim3(24, 32), 256, 0, stream>>>(x, Wq, Wk, Wv, qkv, 2048, 3072, 2048, 2560);
    rope_feat_k<<<20480, 256, 0, stream>>>(qkv, cost, sint, qf, kf);
    copy_v_k<<<2048, 256, 0, stream>>>(qkv, vv);
    chunk_kv_k<<<B_ * KVH_ * NC_, 256, 0, stream>>>(kf, vv, kvc, zc);
    chunk_scan_k<<<B_ * KVH_, 256, 0, stream>>>(kvc, zc);
    chunk_out_k<<<B_ * H_ * NC_, 256, 0, stream>>>(qf, kf, vv, kvc, zc, attn);
    // O projection: M=4096, N=2048, K=2048
    gemm_xwt_k<<<dim3(16, 32), 256, 0, stream>>>(attn, Wo, nullptr, nullptr, out, 2048, 2048, 1 << 30, 1 << 30);
}

// Round 4
// 558.757 us; speedup vs baseline: 2.3168x; 2.3168x over previous
//
#include <hip/hip_runtime.h>
#include <math.h>
#include <stdint.h>

#define B_ 2
#define S_ 2048
#define DM_ 2048
#define H_ 16
#define KVH_ 4
#define HD_ 128
#define NC_ 16
#define CHK_ 128
#define EPS_ 1e-6f
#define GK_ 2048          // K dim of both big GEMMs
#define NT_ (GK_ / 32)    // K-tiles of 32

typedef __attribute__((ext_vector_type(8))) short short8;   // 8 bf16 (4 VGPR)
typedef __attribute__((ext_vector_type(4))) float f32x4;

// async global->LDS, 16B per lane; LDS dst wave-uniform base + lane*16
#define GLOAD16(gsrc, sdst) \
    __builtin_amdgcn_global_load_lds((const __attribute__((address_space(1))) unsigned int*)(gsrc), \
                                     (__attribute__((address_space(3))) unsigned int*)(sdst), 16, 0, 0)

// ------------------------------------------------------------------ RoPE tables
__global__ __launch_bounds__(256) void rope_tables_k(float* __restrict__ cost,
                                                     float* __restrict__ sint) {
    int idx = blockIdx.x * 256 + threadIdx.x;      // S_*64 exact
    int j = idx & 63;
    int s = idx >> 6;
    float inv_freq = powf(10000.0f, -(float)(2 * j) / 128.0f);
    float f = (float)s * inv_freq;
    cost[idx] = cosf(f);
    sint[idx] = sinf(f);
}

// ------------------------------------------------------------------ fp32 -> packed hi/lo bf16
// layout per row of K: [K/8 groups][ hi: 8 bf16 (16B) | lo: 8 bf16 (16B) ]
// hi = truncate-to-bf16(x) (residual exact), lo = truncate-to-bf16(x - hi)
__global__ __launch_bounds__(256) void split_k(const float* __restrict__ in,
                                               unsigned int* __restrict__ outp, int ngrp)
{
    int g = blockIdx.x * 256 + threadIdx.x;
    if (g >= ngrp) return;
    const float* p = in + (size_t)g * 8;
    float x[8];
    *(float4*)&x[0] = *(const float4*)p;
    *(float4*)&x[4] = *(const float4*)(p + 4);
    unsigned int hiw[4], low[4];
#pragma unroll
    for (int w = 0; w < 4; w++) {
        unsigned int b0 = __float_as_uint(x[2 * w]);
        unsigned int b1 = __float_as_uint(x[2 * w + 1]);
        unsigned int h0 = b0 & 0xFFFF0000u, h1 = b1 & 0xFFFF0000u;
        hiw[w] = (h0 >> 16) | h1;
        float r0 = x[2 * w] - __uint_as_float(h0);
        float r1 = x[2 * w + 1] - __uint_as_float(h1);
        low[w] = (__float_as_uint(r0) >> 16) | (__float_as_uint(r1) & 0xFFFF0000u);
    }
    unsigned int* op = outp + (size_t)g * 8;
    *(uint4*)op       = make_uint4(hiw[0], hiw[1], hiw[2], hiw[3]);
    *(uint4*)(op + 4) = make_uint4(low[0], low[1], low[2], low[3]);
}

// ------------------------------------------------------------------ bf16x3 MFMA GEMM
// Y[m,n] = sum_k A[m,k] W[n,k], A/W pre-split packed hi/lo (rowbytes = K*4).
// 128x128 tile, BK=32, 4 waves (2x2 of 64x64), 16x16x32_bf16, dbuf LDS 64KB.
__global__ __launch_bounds__(256, 2) void gemm3_k(
    const char* __restrict__ Apk, const char* __restrict__ W0,
    const char* __restrict__ W1, const char* __restrict__ W2,
    float* __restrict__ Y, int ldY, int nend0, int nend1, int nbx)
{
    __shared__ __attribute__((aligned(16))) char smem[65536];  // 2 x (A 16K | W 16K)

    // XCD-bijective swizzle (gridDim.x % 8 == 0 by construction)
    int nwg = gridDim.x;
    int bid = blockIdx.x;
    int swz = (bid & 7) * (nwg >> 3) + (bid >> 3);
    int by = swz / nbx, bx = swz % nbx;
    const int m0 = by * 128, n0 = bx * 128;

    const char* Wsel;
    int nw;
    if (n0 < nend0)      { Wsel = W0; nw = n0; }
    else if (n0 < nend1) { Wsel = W1; nw = n0 - nend0; }
    else                 { Wsel = W2; nw = n0 - nend1; }

    const int tid = threadIdx.x;
    const int lane = tid & 63;
    const int wv = tid >> 6;            // wave 0..3
    const int wr = wv >> 1, wc = wv & 1;

    // ---- staging source pointers (per lane), swizzled global slot: s ^ (row&7)
    const int r8 = lane >> 3, sl = lane & 7;
    const char* ap[4];
    const char* wp[4];
    int adst[4], wdst[4];
#pragma unroll
    for (int i = 0; i < 4; i++) {
        int rowA = wv * 32 + i * 8 + r8;     // 0..127 (each wave stages 32 rows)
        ap[i] = Apk + (size_t)(m0 + rowA) * (GK_ * 4) + (size_t)((sl ^ (rowA & 7)) * 16);
        wp[i] = Wsel + (size_t)(nw + rowA) * (GK_ * 4) + (size_t)((sl ^ (rowA & 7)) * 16);
        adst[i] = wv * 4096 + i * 1024;
        wdst[i] = 16384 + wv * 4096 + i * 1024;
    }

    // ---- fragment read offsets (per lane), bytes within buffer
    const int lrow = lane & 15, lg = lane >> 4, lc7 = lane & 7;
    const int aoff = (wr * 64 + lrow) * 128 + ((((lg << 1)) ^ lc7) << 4);
    const int woff = 16384 + (wc * 64 + lrow) * 128 + ((((lg << 1)) ^ lc7) << 4);

    f32x4 acc[4][4];
#pragma unroll
    for (int i = 0; i < 4; i++)
#pragma unroll
        for (int j = 0; j < 4; j++) acc[i][j] = (f32x4)(0.f);

    // prologue: stage tile 0 into buf0
#pragma unroll
    for (int i = 0; i < 4; i++) {
        GLOAD16(ap[i], smem + adst[i]);
        GLOAD16(wp[i], smem + wdst[i]);
    }
    __syncthreads();

    for (int kt = 0; kt < NT_; ++kt) {
        const int cur = kt & 1;
        // prefetch next tile into the other buffer
        if (kt + 1 < NT_) {
            const size_t koff = (size_t)(kt + 1) * 128;
            const int nb = (cur ^ 1) * 32768;
#pragma unroll
            for (int i = 0; i < 4; i++) {
                GLOAD16(ap[i] + koff, smem + nb + adst[i]);
                GLOAD16(wp[i] + koff, smem + nb + wdst[i]);
            }
        }
        // compute current tile
        const char* sb = smem + cur * 32768;
        short8 ah[4], al[4], bh[4], bl[4];
#pragma unroll
        for (int f = 0; f < 4; f++) {
            ah[f] = *(const short8*)(sb + (aoff)        + f * 2048);
            al[f] = *(const short8*)(sb + (aoff ^ 16)   + f * 2048);
            bh[f] = *(const short8*)(sb + (woff)        + f * 2048);
            bl[f] = *(const short8*)(sb + (woff ^ 16)   + f * 2048);
        }
#pragma unroll
        for (int i = 0; i < 4; i++)
#pragma unroll
            for (int j = 0; j < 4; j++) {
                acc[i][j] = __builtin_amdgcn_mfma_f32_16x16x32_bf16(ah[i], bh[j], acc[i][j], 0, 0, 0);
                acc[i][j] = __builtin_amdgcn_mfma_f32_16x16x32_bf16(ah[i], bl[j], acc[i][j], 0, 0, 0);
                acc[i][j] = __builtin_amdgcn_mfma_f32_16x16x32_bf16(al[i], bh[j], acc[i][j], 0, 0, 0);
            }
        __syncthreads();
    }

    // epilogue: C/D layout col = lane&15, row = (lane>>4)*4 + reg
#pragma unroll
    for (int i = 0; i < 4; i++) {
        int r0 = m0 + wr * 64 + i * 16 + lg * 4;
#pragma unroll
        for (int j = 0; j < 4; j++) {
            int cc = n0 + wc * 64 + j * 16 + lrow;
            f32x4 v = acc[i][j];
            Y[(size_t)(r0 + 0) * ldY + cc] = v[0];
            Y[(size_t)(r0 + 1) * ldY + cc] = v[1];
            Y[(size_t)(r0 + 2) * ldY + cc] = v[2];
            Y[(size_t)(r0 + 3) * ldY + cc] = v[3];
        }
    }
}

// ------------------------------------------------------------------ RoPE + elu(+1) for q,k
__global__ __launch_bounds__(256) void rope_feat_k(
    const float* __restrict__ qkv, const float* __restrict__ cost,
    const float* __restrict__ sint, float* __restrict__ qf, float* __restrict__ kf)
{
    int idx = blockIdx.x * 256 + threadIdx.x;  // B_*S_*20*64 exact
    int j = idx & 63;
    int t = idx >> 6;
    int hh = t % 20;
    int t2 = t / 20;
    int s = t2 % S_;
    int b = t2 / S_;
    const float* row = qkv + (size_t)(b * S_ + s) * 3072;
    int col;
    float* outp;
    if (hh < H_) {
        col = hh * HD_;
        outp = qf + ((size_t)(b * H_ + hh) * S_ + s) * HD_;
    } else {
        int kv = hh - H_;
        col = 2048 + kv * HD_;
        outp = kf + ((size_t)(b * KVH_ + kv) * S_ + s) * HD_;
    }
    float x1 = row[col + j];
    float x2 = row[col + j + 64];
    float cs = cost[s * 64 + j];
    float sn = sint[s * 64 + j];
    float o1 = x1 * cs - x2 * sn;
    float o2 = x2 * cs + x1 * sn;
    o1 = o1 > 0.f ? o1 + 1.f : expf(o1);
    o2 = o2 > 0.f ? o2 + 1.f : expf(o2);
    outp[j] = o1;
    outp[j + 64] = o2;
}

// ------------------------------------------------------------------ V layout transform
__global__ __launch_bounds__(256) void copy_v_k(const float* __restrict__ qkv,
                                                float* __restrict__ v)
{
    int idx = blockIdx.x * 256 + threadIdx.x;
    int d4 = idx & 31;
    int t = idx >> 5;
    int kv = t & 3;
    int t2 = t >> 2;
    int s = t2 % S_;
    int b = t2 / S_;
    float4 val = *(const float4*)(qkv + (size_t)(b * S_ + s) * 3072 + 2560 + kv * HD_ + d4 * 4);
    *(float4*)(v + ((size_t)(b * KVH_ + kv) * S_ + s) * HD_ + d4 * 4) = val;
}

// ------------------------------------------------------------------ per-chunk KV summaries
__global__ __launch_bounds__(256) void chunk_kv_k(
    const float* __restrict__ kf, const float* __restrict__ vv,
    float* __restrict__ kvc, float* __restrict__ zc)
{
    int bx = blockIdx.x;
    int c = bx % NC_;
    int bkv = bx / NC_;
    const float* kp = kf + ((size_t)bkv * S_ + c * CHK_) * HD_;
    const float* vp = vv + ((size_t)bkv * S_ + c * CHK_) * HD_;
    __shared__ __attribute__((aligned(16))) float ks[CHK_][HD_ + 4];
    __shared__ __attribute__((aligned(16))) float vs[CHK_][HD_ + 4];
    int tid = threadIdx.x, tx = tid & 15, ty = tid >> 4;
#pragma unroll
    for (int it = 0; it < 16; it++) {
        int idx = it * 256 + tid;
        int r = idx >> 5, c4 = idx & 31;
        *(float4*)&ks[r][c4 * 4] = *(const float4*)(kp + (size_t)r * HD_ + c4 * 4);
        *(float4*)&vs[r][c4 * 4] = *(const float4*)(vp + (size_t)r * HD_ + c4 * 4);
    }
    __syncthreads();
    float acc[8][8];
#pragma unroll
    for (int i = 0; i < 8; i++)
#pragma unroll
        for (int j = 0; j < 8; j++) acc[i][j] = 0.f;
    for (int j = 0; j < CHK_; j++) {
        float a[8], b[8];
        *(float4*)&a[0] = *(const float4*)&ks[j][ty * 8];
        *(float4*)&a[4] = *(const float4*)&ks[j][ty * 8 + 4];
        *(float4*)&b[0] = *(const float4*)&vs[j][tx * 8];
        *(float4*)&b[4] = *(const float4*)&vs[j][tx * 8 + 4];
#pragma unroll
        for (int i = 0; i < 8; i++)
#pragma unroll
            for (int jj = 0; jj < 8; jj++)
                acc[i][jj] = fmaf(a[i], b[jj], acc[i][jj]);
    }
    float* outp = kvc + (size_t)bx * (HD_ * HD_);
#pragma unroll
    for (int i = 0; i < 8; i++) {
        float* op = outp + (size_t)(ty * 8 + i) * HD_ + tx * 8;
        *(float4*)op       = make_float4(acc[i][0], acc[i][1], acc[i][2], acc[i][3]);
        *(float4*)(op + 4) = make_float4(acc[i][4], acc[i][5], acc[i][6], acc[i][7]);
    }
    if (tid < CHK_) {
        float z = 0.f;
        for (int j = 0; j < CHK_; j++) z += ks[j][tid];
        zc[(size_t)bx * HD_ + tid] = z;
    }
}

// ------------------------------------------------------------------ exclusive chunk scan
__global__ __launch_bounds__(256) void chunk_scan_k(float* __restrict__ kvc,
                                                    float* __restrict__ zc)
{
    int bkv = blockIdx.x;
    float* base = kvc + (size_t)bkv * NC_ * HD_ * HD_;
    float* zbase = zc + (size_t)bkv * NC_ * HD_;
    int tid = threadIdx.x;
    float acc[64];
#pragma unroll
    for (int i = 0; i < 64; i++) acc[i] = 0.f;
    float zacc = 0.f;
    for (int c = 0; c < NC_; c++) {
        float* p = base + (size_t)c * HD_ * HD_;
#pragma unroll
        for (int i = 0; i < 64; i++) {
            float cur = p[i * 256 + tid];
            p[i * 256 + tid] = acc[i];
            acc[i] += cur;
        }
        if (tid < CHK_) {
            float* zp = zbase + c * HD_ + tid;
            float zcur = *zp;
            *zp = zacc;
            zacc += zcur;
        }
    }
}

// ------------------------------------------------------------------ per-chunk output
// Writes packed hi/lo bf16 rows (gemm3 input layout): row 8192B = 256 kgroups x 32B.
__global__ __launch_bounds__(256, 1) void chunk_out_k(
    const float* __restrict__ qf, const float* __restrict__ kf,
    const float* __restrict__ vv, const float* __restrict__ kvpre,
    const float* __restrict__ zpre, float* __restrict__ attn)
{
    int bx = blockIdx.x;
    int c = bx & 15;
    int h = (bx >> 4) & 15;
    int b = bx >> 8;
    int kv = h >> 2;
    int bkvc = (b * KVH_ + kv) * NC_ + c;
    const float* qp = qf + ((size_t)(b * H_ + h) * S_ + c * CHK_) * HD_;
    const float* kp = kf + ((size_t)(b * KVH_ + kv) * S_ + c * CHK_) * HD_;
    const float* vp = vv + ((size_t)(b * KVH_ + kv) * S_ + c * CHK_) * HD_;
    const float* sp = kvpre + (size_t)bkvc * HD_ * HD_;
    const float* zp = zpre + (size_t)bkvc * HD_;

    __shared__ __attribute__((aligned(16))) float smem[38272];
    float* Qt    = smem;            // [128][132] transposed
    float* KtA   = smem + 16896;    // [128][132] Kt then At
    float* Vs    = smem + 33792;    // [32][132]
    float* den_s = smem + 38016;    // [128]
    float* zs    = smem + 38144;    // [128]

    int tid = threadIdx.x, tx = tid & 15, ty = tid >> 4;

#pragma unroll
    for (int it = 0; it < 16; it++) {
        int idx = it * 256 + tid;
        int r = idx >> 5, c4 = idx & 31;
        float4 a = *(const float4*)(qp + (size_t)r * HD_ + c4 * 4);
        float4 kq = *(const float4*)(kp + (size_t)r * HD_ + c4 * 4);
        Qt[(c4 * 4 + 0) * 132 + r] = a.x;  Qt[(c4 * 4 + 1) * 132 + r] = a.y;
        Qt[(c4 * 4 + 2) * 132 + r] = a.z;  Qt[(c4 * 4 + 3) * 132 + r] = a.w;
        KtA[(c4 * 4 + 0) * 132 + r] = kq.x; KtA[(c4 * 4 + 1) * 132 + r] = kq.y;
        KtA[(c4 * 4 + 2) * 132 + r] = kq.z; KtA[(c4 * 4 + 3) * 132 + r] = kq.w;
    }
    if (tid < CHK_) zs[tid] = zp[tid];
    __syncthreads();

    float acc1[8][8];
#pragma unroll
    for (int i = 0; i < 8; i++)
#pragma unroll
        for (int j = 0; j < 8; j++) acc1[i][j] = 0.f;
    for (int d = 0; d < HD_; d++) {
        float a[8], bb[8];
        *(float4*)&a[0]  = *(const float4*)&Qt[d * 132 + ty * 8];
        *(float4*)&a[4]  = *(const float4*)&Qt[d * 132 + ty * 8 + 4];
        *(float4*)&bb[0] = *(const float4*)&KtA[d * 132 + tx * 8];
        *(float4*)&bb[4] = *(const float4*)&KtA[d * 132 + tx * 8 + 4];
#pragma unroll
        for (int i = 0; i < 8; i++)
#pragma unroll
            for (int j = 0; j < 8; j++)
                acc1[i][j] = fmaf(a[i], bb[j], acc1[i][j]);
    }
    __syncthreads();

    float rs[8];
#pragma unroll
    for (int i = 0; i < 8; i++) rs[i] = 0.f;
#pragma unroll
    for (int j = 0; j < 8; j++) {
        int gj = tx * 8 + j;
        float e0 = (gj <= ty * 8 + 0) ? acc1[0][j] : 0.f; rs[0] += e0;
        float e1 = (gj <= ty * 8 + 1) ? acc1[1][j] : 0.f; rs[1] += e1;
        float e2 = (gj <= ty * 8 + 2) ? acc1[2][j] : 0.f; rs[2] += e2;
        float e3 = (gj <= ty * 8 + 3) ? acc1[3][j] : 0.f; rs[3] += e3;
        float e4 = (gj <= ty * 8 + 4) ? acc1[4][j] : 0.f; rs[4] += e4;
        float e5 = (gj <= ty * 8 + 5) ? acc1[5][j] : 0.f; rs[5] += e5;
        float e6 = (gj <= ty * 8 + 6) ? acc1[6][j] : 0.f; rs[6] += e6;
        float e7 = (gj <= ty * 8 + 7) ? acc1[7][j] : 0.f; rs[7] += e7;
        *(float4*)&KtA[gj * 132 + ty * 8]     = make_float4(e0, e1, e2, e3);
        *(float4*)&KtA[gj * 132 + ty * 8 + 4] = make_float4(e4, e5, e6, e7);
    }
#pragma unroll
    for (int m = 1; m < 16; m <<= 1) {
#pragma unroll
        for (int i = 0; i < 8; i++) rs[i] += __shfl_xor(rs[i], m, 64);
    }
    if (tx == 0) {
#pragma unroll
        for (int i = 0; i < 8; i++) den_s[ty * 8 + i] = rs[i];
    }
    __syncthreads();
    if (tid < CHK_) {
        float d2 = 0.f;
        for (int e = 0; e < HD_; e++) d2 = fmaf(Qt[e * 132 + tid], zs[e], d2);
        den_s[tid] += d2 + EPS_;
    }

    float acc2[8][8];
#pragma unroll
    for (int i = 0; i < 8; i++)
#pragma unroll
        for (int j = 0; j < 8; j++) acc2[i][j] = 0.f;
    for (int jt = 0; jt < 4; jt++) {
        float4 vld[4];
#pragma unroll
        for (int it = 0; it < 4; it++) {
            int idx = it * 256 + tid;
            int r = idx >> 5, c4 = idx & 31;
            vld[it] = *(const float4*)(vp + (size_t)(jt * 32 + r) * HD_ + c4 * 4);
        }
        __syncthreads();
#pragma unroll
        for (int it = 0; it < 4; it++) {
            int idx = it * 256 + tid;
            int r = idx >> 5, c4 = idx & 31;
            *(float4*)&Vs[r * 132 + c4 * 4] = vld[it];
        }
        __syncthreads();
        for (int j = 0; j < 32; j++) {
            int gj = jt * 32 + j;
            float a[8], bb[8];
            *(float4*)&a[0]  = *(const float4*)&KtA[gj * 132 + ty * 8];
            *(float4*)&a[4]  = *(const float4*)&KtA[gj * 132 + ty * 8 + 4];
            *(float4*)&bb[0] = *(const float4*)&Vs[j * 132 + tx * 8];
            *(float4*)&bb[4] = *(const float4*)&Vs[j * 132 + tx * 8 + 4];
#pragma unroll
            for (int i = 0; i < 8; i++)
#pragma unroll
                for (int jj = 0; jj < 8; jj++)
                    acc2[i][jj] = fmaf(a[i], bb[jj], acc2[i][jj]);
        }
    }
    for (int et = 0; et < 4; et++) {
        float4 vld[4];
#pragma unroll
        for (int it = 0; it < 4; it++) {
            int idx = it * 256 + tid;
            int r = idx >> 5, c4 = idx & 31;
            vld[it] = *(const float4*)(sp + (size_t)(et * 32 + r) * HD_ + c4 * 4);
        }
        __syncthreads();
#pragma unroll
        for (int it = 0; it < 4; it++) {
            int idx = it * 256 + tid;
            int r = idx >> 5, c4 = idx & 31;
            *(float4*)&Vs[r * 132 + c4 * 4] = vld[it];
        }
        __syncthreads();
        for (int e = 0; e < 32; e++) {
            int ge = et * 32 + e;
            float a[8], bb[8];
            *(float4*)&a[0]  = *(const float4*)&Qt[ge * 132 + ty * 8];
            *(float4*)&a[4]  = *(const float4*)&Qt[ge * 132 + ty * 8 + 4];
            *(float4*)&bb[0] = *(const float4*)&Vs[e * 132 + tx * 8];
            *(float4*)&bb[4] = *(const float4*)&Vs[e * 132 + tx * 8 + 4];
#pragma unroll
            for (int i = 0; i < 8; i++)
#pragma unroll
                for (int jj = 0; jj < 8; jj++)
                    acc2[i][jj] = fmaf(a[i], bb[jj], acc2[i][jj]);
        }
    }

    int s0 = c * CHK_;
#pragma unroll
    for (int i = 0; i < 8; i++) {
        int gi = ty * 8 + i;
        float inv = 1.0f / den_s[gi];
        float o[8];
#pragma unroll
        for (int jj = 0; jj < 8; jj++) o[jj] = acc2[i][jj] * inv;
        unsigned int hiw[4], low[4];
#pragma unroll
        for (int w = 0; w < 4; w++) {
            unsigned int b0 = __float_as_uint(o[2 * w]);
            unsigned int b1 = __float_as_uint(o[2 * w + 1]);
            unsigned int h0 = b0 & 0xFFFF0000u, h1 = b1 & 0xFFFF0000u;
            hiw[w] = (h0 >> 16) | h1;
            float r0 = o[2 * w] - __uint_as_float(h0);
            float r1 = o[2 * w + 1] - __uint_as_float(h1);
            low[w] = (__float_as_uint(r0) >> 16) | (__float_as_uint(r1) & 0xFFFF0000u);
        }
        // packed row: 256 kgroups x 32B; kgroup = h*16 + tx
        char* op = (char*)attn + ((size_t)(b * S_ + s0 + gi) * 256 + h * 16 + tx) * 32;
        *(uint4*)op        = make_uint4(hiw[0], hiw[1], hiw[2], hiw[3]);
        *(uint4*)(op + 16) = make_uint4(low[0], low[1], low[2], low[3]);
    }
}

// ------------------------------------------------------------------ launch
// ws layout (floats) — exactly the R1 footprint (27,541,504 f = 110.17 MB),
// with lifetime-based aliasing:
//   [0,        8388608)  xpk      -> qf        (xpk dead after QKV gemm)
//   [8388608, 12582912)  wqpk     -> kf | vv   (wqpk dead after QKV gemm)
//   [12582912,14680064)  wkpk,wvpk-> kvc       (dead after QKV gemm)
//   [14680064,27262976)  qkv fp32 -> attnpk [14680064,23068672) + wopk [23068672,...)
//   [27262976,27525120)  cos | sin tables
//   [27525120,27541504)  zc
extern "C" void kernel_launch(void* const* d_in, const int* in_sizes, int n_in,
                              void* d_out, int out_size, void* d_ws, size_t ws_size,
                              hipStream_t stream)
{
    (void)in_sizes; (void)n_in; (void)out_size; (void)ws_size;
    const float* x  = (const float*)d_in[0];
    const float* Wq = (const float*)d_in[1];
    const float* Wk = (const float*)d_in[2];
    const float* Wv = (const float*)d_in[3];
    const float* Wo = (const float*)d_in[4];
    float* out = (float*)d_out;
    float* ws  = (float*)d_ws;

    float* xpk   = ws;                  // phase A
    float* wqpk  = ws + 8388608;
    float* wkpk  = ws + 12582912;
    float* wvpk  = ws + 13631488;
    float* qkv   = ws + 14680064;       // fp32 QKV output [4096][3072]
    float* cost  = ws + 27262976;
    float* sint  = ws + 27394048;
    float* zc    = ws + 27525120;

    float* qf    = xpk;                 // phase B aliases
    float* kf    = ws + 8388608;
    float* vv    = ws + 10485760;
    float* kvc   = ws + 12582912;
    float* attnpk = qkv;                // lower 8.4M of qkv region
    float* wopk  = ws + 23068672;       // upper 4.2M of qkv region

    rope_tables_k<<<512, 256, 0, stream>>>(cost, sint);

    // phase A: pack inputs, QKV projection (M=4096, N=3072=q|k|v, K=2048)
    split_k<<<4096, 256, 0, stream>>>(x,  (unsigned int*)xpk,  1048576);
    split_k<<<2048, 256, 0, stream>>>(Wq, (unsigned int*)wqpk, 524288);
    split_k<<<512,  256, 0, stream>>>(Wk, (unsigned int*)wkpk, 131072);
    split_k<<<512,  256, 0, stream>>>(Wv, (unsigned int*)wvpk, 131072);
    gemm3_k<<<768, 256, 0, stream>>>((const char*)xpk, (const char*)wqpk,
                                     (const char*)wkpk, (const char*)wvpk,
                                     qkv, 3072, 2048, 2560, 24);

    // phase B: RoPE + feature map (qf overwrites xpk; kf/vv overwrite wqpk)
    rope_feat_k<<<20480, 256, 0, stream>>>(qkv, cost, sint, qf, kf);
    copy_v_k<<<2048, 256, 0, stream>>>(qkv, vv);
    // qkv fp32 now dead -> pack Wo into its upper part
    split_k<<<2048, 256, 0, stream>>>(Wo, (unsigned int*)wopk, 524288);

    // phase C: chunked linear attention
    chunk_kv_k<<<B_ * KVH_ * NC_, 256, 0, stream>>>(kf, vv, kvc, zc);
    chunk_scan_k<<<B_ * KVH_, 256, 0, stream>>>(kvc, zc);
    chunk_out_k<<<B_ * H_ * NC_, 256, 0, stream>>>(qf, kf, vv, kvc, zc, attnpk);

    // phase D: O projection (M=4096, N=2048, K=2048)
    gemm3_k<<<512, 256, 0, stream>>>((const char*)attnpk, (const char*)wopk,
                                     (const char*)wopk, (const char*)wopk,
                                     out, 2048, 1 << 30, 1 << 30, 16);
}

// Round 5
// 459.061 us; speedup vs baseline: 2.8200x; 1.2172x over previous
//
#include <hip/hip_runtime.h>
#include <math.h>
#include <stdint.h>

#define B_ 2
#define S_ 2048
#define H_ 16
#define KVH_ 4
#define HD_ 128
#define NC_ 16
#define CHK_ 128
#define EPS_ 1e-6f
#define GK_ 2048          // K dim of both big GEMMs
#define NT_ (GK_ / 32)    // K-tiles of 32

typedef __attribute__((ext_vector_type(8))) short short8;   // 8 bf16 (4 VGPR)
typedef __attribute__((ext_vector_type(4))) float f32x4;

// async global->LDS, 16B per lane; LDS dst wave-uniform base + lane*16
#define GLOAD16(gsrc, sdst) \
    __builtin_amdgcn_global_load_lds((const __attribute__((address_space(1))) unsigned int*)(gsrc), \
                                     (__attribute__((address_space(3))) unsigned int*)(sdst), 16, 0, 0)

static __device__ __forceinline__ float bf2f(unsigned int u) {
    return __uint_as_float(u << 16);
}

// 8 fp32 -> hi/lo bf16 uint4 pair (truncation split, residual exact)
static __device__ __forceinline__ void pack8(const float* v, uint4& hi, uint4& lo) {
    unsigned int h[4], l[4];
#pragma unroll
    for (int w = 0; w < 4; w++) {
        unsigned int b0 = __float_as_uint(v[2 * w]);
        unsigned int b1 = __float_as_uint(v[2 * w + 1]);
        unsigned int h0 = b0 & 0xFFFF0000u, h1 = b1 & 0xFFFF0000u;
        h[w] = (h0 >> 16) | h1;
        float r0 = v[2 * w] - __uint_as_float(h0);
        float r1 = v[2 * w + 1] - __uint_as_float(h1);
        l[w] = (__float_as_uint(r0) >> 16) | (__float_as_uint(r1) & 0xFFFF0000u);
    }
    hi = make_uint4(h[0], h[1], h[2], h[3]);
    lo = make_uint4(l[0], l[1], l[2], l[3]);
}

// 8 fp32 -> hi/lo short8 MFMA fragments
static __device__ __forceinline__ void split8_frag(const float* p, short8& hi, short8& lo) {
#pragma unroll
    for (int e = 0; e < 8; e++) {
        unsigned int b = __float_as_uint(p[e]);
        unsigned int h = b & 0xFFFF0000u;
        hi[e] = (short)(h >> 16);
        float r = p[e] - __uint_as_float(h);
        lo[e] = (short)(__float_as_uint(r) >> 16);
    }
}

// ------------------------------------------------------------------ RoPE tables
__global__ __launch_bounds__(256) void rope_tables_k(float* __restrict__ cost,
                                                     float* __restrict__ sint) {
    int idx = blockIdx.x * 256 + threadIdx.x;      // S_*64 exact
    int j = idx & 63;
    int s = idx >> 6;
    float inv_freq = powf(10000.0f, -(float)(2 * j) / 128.0f);
    float f = (float)s * inv_freq;
    cost[idx] = cosf(f);
    sint[idx] = sinf(f);
}

// ------------------------------------------------------------------ fp32 -> packed hi/lo bf16
__global__ __launch_bounds__(256) void split_k(const float* __restrict__ in,
                                               unsigned int* __restrict__ outp, int ngrp)
{
    int g = blockIdx.x * 256 + threadIdx.x;
    if (g >= ngrp) return;
    const float* p = in + (size_t)g * 8;
    float x[8];
    *(float4*)&x[0] = *(const float4*)p;
    *(float4*)&x[4] = *(const float4*)(p + 4);
    uint4 hi, lo;
    pack8(x, hi, lo);
    unsigned int* op = outp + (size_t)g * 8;
    *(uint4*)op       = hi;
    *(uint4*)(op + 4) = lo;
}

// ------------------------------------------------------------------ bf16x3 MFMA GEMM (unchanged from R4)
__global__ __launch_bounds__(256, 2) void gemm3_k(
    const char* __restrict__ Apk, const char* __restrict__ W0,
    const char* __restrict__ W1, const char* __restrict__ W2,
    float* __restrict__ Y, int ldY, int nend0, int nend1, int nbx)
{
    __shared__ __attribute__((aligned(16))) char smem[65536];

    int nwg = gridDim.x;
    int bid = blockIdx.x;
    int swz = (bid & 7) * (nwg >> 3) + (bid >> 3);
    int by = swz / nbx, bx = swz % nbx;
    const int m0 = by * 128, n0 = bx * 128;

    const char* Wsel;
    int nw;
    if (n0 < nend0)      { Wsel = W0; nw = n0; }
    else if (n0 < nend1) { Wsel = W1; nw = n0 - nend0; }
    else                 { Wsel = W2; nw = n0 - nend1; }

    const int tid = threadIdx.x;
    const int lane = tid & 63;
    const int wv = tid >> 6;
    const int wr = wv >> 1, wc = wv & 1;

    const int r8 = lane >> 3, sl = lane & 7;
    const char* ap[4];
    const char* wp[4];
    int adst[4], wdst[4];
#pragma unroll
    for (int i = 0; i < 4; i++) {
        int rowA = wv * 32 + i * 8 + r8;
        ap[i] = Apk + (size_t)(m0 + rowA) * (GK_ * 4) + (size_t)((sl ^ (rowA & 7)) * 16);
        wp[i] = Wsel + (size_t)(nw + rowA) * (GK_ * 4) + (size_t)((sl ^ (rowA & 7)) * 16);
        adst[i] = wv * 4096 + i * 1024;
        wdst[i] = 16384 + wv * 4096 + i * 1024;
    }

    const int lrow = lane & 15, lg = lane >> 4, lc7 = lane & 7;
    const int aoff = (wr * 64 + lrow) * 128 + ((((lg << 1)) ^ lc7) << 4);
    const int woff = 16384 + (wc * 64 + lrow) * 128 + ((((lg << 1)) ^ lc7) << 4);

    f32x4 acc[4][4];
#pragma unroll
    for (int i = 0; i < 4; i++)
#pragma unroll
        for (int j = 0; j < 4; j++) acc[i][j] = (f32x4)(0.f);

#pragma unroll
    for (int i = 0; i < 4; i++) {
        GLOAD16(ap[i], smem + adst[i]);
        GLOAD16(wp[i], smem + wdst[i]);
    }
    __syncthreads();

    for (int kt = 0; kt < NT_; ++kt) {
        const int cur = kt & 1;
        if (kt + 1 < NT_) {
            const size_t koff = (size_t)(kt + 1) * 128;
            const int nb = (cur ^ 1) * 32768;
#pragma unroll
            for (int i = 0; i < 4; i++) {
                GLOAD16(ap[i] + koff, smem + nb + adst[i]);
                GLOAD16(wp[i] + koff, smem + nb + wdst[i]);
            }
        }
        const char* sb = smem + cur * 32768;
        short8 ah[4], al[4], bh[4], bl[4];
#pragma unroll
        for (int f = 0; f < 4; f++) {
            ah[f] = *(const short8*)(sb + (aoff)        + f * 2048);
            al[f] = *(const short8*)(sb + (aoff ^ 16)   + f * 2048);
            bh[f] = *(const short8*)(sb + (woff)        + f * 2048);
            bl[f] = *(const short8*)(sb + (woff ^ 16)   + f * 2048);
        }
#pragma unroll
        for (int i = 0; i < 4; i++)
#pragma unroll
            for (int j = 0; j < 4; j++) {
                acc[i][j] = __builtin_amdgcn_mfma_f32_16x16x32_bf16(ah[i], bh[j], acc[i][j], 0, 0, 0);
                acc[i][j] = __builtin_amdgcn_mfma_f32_16x16x32_bf16(ah[i], bl[j], acc[i][j], 0, 0, 0);
                acc[i][j] = __builtin_amdgcn_mfma_f32_16x16x32_bf16(al[i], bh[j], acc[i][j], 0, 0, 0);
            }
        __syncthreads();
    }

#pragma unroll
    for (int i = 0; i < 4; i++) {
        int r0 = m0 + wr * 64 + i * 16 + lg * 4;
#pragma unroll
        for (int j = 0; j < 4; j++) {
            int cc = n0 + wc * 64 + j * 16 + lrow;
            f32x4 v = acc[i][j];
            Y[(size_t)(r0 + 0) * ldY + cc] = v[0];
            Y[(size_t)(r0 + 1) * ldY + cc] = v[1];
            Y[(size_t)(r0 + 2) * ldY + cc] = v[2];
            Y[(size_t)(r0 + 3) * ldY + cc] = v[3];
        }
    }
}

// ------------------------------------------------------------------ RoPE + elu(+1), emit packed hi/lo rows
// thread = (row, kgroup g of 8 d's). qf/kf rows are 512B: 16 kgroups x [hi 16B | lo 16B].
__global__ __launch_bounds__(256) void rope_feat_k(
    const float* __restrict__ qkv, const float* __restrict__ cost,
    const float* __restrict__ sint, char* __restrict__ qfpk, char* __restrict__ kfpk)
{
    int idx = blockIdx.x * 256 + threadIdx.x;  // B_*S_*20*16 exact
    int g = idx & 15;
    int t = idx >> 4;
    int hh = t % 20;
    int t2 = t / 20;
    int s = t2 % S_;
    int b = t2 / S_;
    const float* row = qkv + (size_t)(b * S_ + s) * 3072;
    int col;
    char* outp;
    if (hh < H_) {
        col = hh * HD_;
        outp = qfpk + ((size_t)(b * H_ + hh) * S_ + s) * 512;
    } else {
        int kv = hh - H_;
        col = 2048 + kv * HD_;
        outp = kfpk + ((size_t)(b * KVH_ + kv) * S_ + s) * 512;
    }
    int d0 = g * 8;
    int dp = (g < 8) ? d0 + 64 : d0 - 64;
    int j0 = (g < 8) ? d0 : d0 - 64;
    float xa[8], xb[8], o[8];
    *(float4*)&xa[0] = *(const float4*)(row + col + d0);
    *(float4*)&xa[4] = *(const float4*)(row + col + d0 + 4);
    *(float4*)&xb[0] = *(const float4*)(row + col + dp);
    *(float4*)&xb[4] = *(const float4*)(row + col + dp + 4);
#pragma unroll
    for (int e = 0; e < 8; e++) {
        float cs = cost[s * 64 + j0 + e];
        float sn = sint[s * 64 + j0 + e];
        float v = (g < 8) ? (xa[e] * cs - xb[e] * sn) : (xa[e] * cs + xb[e] * sn);
        o[e] = v > 0.f ? v + 1.f : expf(v);
    }
    uint4 hi, lo;
    pack8(o, hi, lo);
    *(uint4*)(outp + g * 32)      = hi;
    *(uint4*)(outp + g * 32 + 16) = lo;
}

// ------------------------------------------------------------------ V: fp32 row-major copy + packed V^T
// vvT layout: [bkv][d=128 rows][S/8=256 kgroups x 32B], row stride 8192B.
__global__ __launch_bounds__(256) void copy_v_k(const float* __restrict__ qkv,
                                                float* __restrict__ vv,
                                                char* __restrict__ vtpk)
{
    __shared__ __attribute__((aligned(16))) float Vt[CHK_][HD_ + 4];
    int bx = blockIdx.x;               // bkv*16 + st
    int st = bx & 15;
    int bkv = bx >> 4;
    int b = bkv >> 2, kv = bkv & 3;
    int tid = threadIdx.x;
#pragma unroll
    for (int it = 0; it < 16; it++) {
        int idx = it * 256 + tid;
        int r = idx >> 5, c4 = idx & 31;
        float4 v = *(const float4*)(qkv + (size_t)(b * S_ + st * CHK_ + r) * 3072 + 2560 + kv * HD_ + c4 * 4);
        *(float4*)(vv + ((size_t)bkv * S_ + st * CHK_ + r) * HD_ + c4 * 4) = v;
        *(float4*)&Vt[r][c4 * 4] = v;
    }
    __syncthreads();
#pragma unroll
    for (int it = 0; it < 2; it++) {
        int t2 = it * 256 + tid;       // 0..511
        int d = t2 & 127, sg = t2 >> 7;
#pragma unroll
        for (int kk = 0; kk < 4; kk++) {
            int kgl = sg * 4 + kk;     // 0..15 (s-kgroup within this 128-s tile)
            float f[8];
#pragma unroll
            for (int e = 0; e < 8; e++) f[e] = Vt[kgl * 8 + e][d];
            uint4 hi, lo;
            pack8(f, hi, lo);
            char* op = vtpk + (size_t)bkv * 1048576 + (size_t)d * 8192 + (size_t)(st * 16 + kgl) * 32;
            *(uint4*)op        = hi;
            *(uint4*)(op + 16) = lo;
        }
    }
}

// ------------------------------------------------------------------ per-chunk KV summaries (K from packed)
__global__ __launch_bounds__(256) void chunk_kv_k(
    const char* __restrict__ kfpk, const float* __restrict__ vv,
    float* __restrict__ kvc, float* __restrict__ zc)
{
    int bx = blockIdx.x;
    int c = bx % NC_;
    int bkv = bx / NC_;
    const char* kp = kfpk + ((size_t)bkv * S_ + c * CHK_) * 512;
    const float* vp = vv + ((size_t)bkv * S_ + c * CHK_) * HD_;
    __shared__ __attribute__((aligned(16))) float ks[CHK_][HD_ + 4];
    __shared__ __attribute__((aligned(16))) float vs[CHK_][HD_ + 4];
    int tid = threadIdx.x, tx = tid & 15, ty = tid >> 4;
#pragma unroll
    for (int it = 0; it < 8; it++) {       // 128 rows x 16 kgroups
        int idx = it * 256 + tid;
        int r = idx >> 4, kg = idx & 15;
        const uint4* sp = (const uint4*)(kp + (size_t)r * 512 + kg * 32);
        uint4 hi = sp[0], lo = sp[1];
        float* d = &ks[r][kg * 8];
        d[0] = bf2f(hi.x & 0xFFFFu) + bf2f(lo.x & 0xFFFFu);
        d[1] = bf2f(hi.x >> 16)     + bf2f(lo.x >> 16);
        d[2] = bf2f(hi.y & 0xFFFFu) + bf2f(lo.y & 0xFFFFu);
        d[3] = bf2f(hi.y >> 16)     + bf2f(lo.y >> 16);
        d[4] = bf2f(hi.z & 0xFFFFu) + bf2f(lo.z & 0xFFFFu);
        d[5] = bf2f(hi.z >> 16)     + bf2f(lo.z >> 16);
        d[6] = bf2f(hi.w & 0xFFFFu) + bf2f(lo.w & 0xFFFFu);
        d[7] = bf2f(hi.w >> 16)     + bf2f(lo.w >> 16);
    }
#pragma unroll
    for (int it = 0; it < 16; it++) {
        int idx = it * 256 + tid;
        int r = idx >> 5, c4 = idx & 31;
        *(float4*)&vs[r][c4 * 4] = *(const float4*)(vp + (size_t)r * HD_ + c4 * 4);
    }
    __syncthreads();
    float acc[8][8];
#pragma unroll
    for (int i = 0; i < 8; i++)
#pragma unroll
        for (int j = 0; j < 8; j++) acc[i][j] = 0.f;
    for (int j = 0; j < CHK_; j++) {
        float a[8], b[8];
        *(float4*)&a[0] = *(const float4*)&ks[j][ty * 8];
        *(float4*)&a[4] = *(const float4*)&ks[j][ty * 8 + 4];
        *(float4*)&b[0] = *(const float4*)&vs[j][tx * 8];
        *(float4*)&b[4] = *(const float4*)&vs[j][tx * 8 + 4];
#pragma unroll
        for (int i = 0; i < 8; i++)
#pragma unroll
            for (int jj = 0; jj < 8; jj++)
                acc[i][jj] = fmaf(a[i], b[jj], acc[i][jj]);
    }
    float* outp = kvc + (size_t)bx * (HD_ * HD_);
#pragma unroll
    for (int i = 0; i < 8; i++) {
        float* op = outp + (size_t)(ty * 8 + i) * HD_ + tx * 8;
        *(float4*)op       = make_float4(acc[i][0], acc[i][1], acc[i][2], acc[i][3]);
        *(float4*)(op + 4) = make_float4(acc[i][4], acc[i][5], acc[i][6], acc[i][7]);
    }
    if (tid < CHK_) {
        float z = 0.f;
        for (int j = 0; j < CHK_; j++) z += ks[j][tid];
        zc[(size_t)bx * HD_ + tid] = z;
    }
}

// ------------------------------------------------------------------ exclusive chunk scan
// 64 blocks (bkv x dgroup of 16 d-cols). Emits packed-transposed exclusive prefix
// kvcT[bkvc][d=128 rows][16 e-kgroups x 32B]; zc prefix in place (fp32).
__global__ __launch_bounds__(256) void chunk_scan_k(const float* __restrict__ kvc,
                                                    char* __restrict__ kvct,
                                                    float* __restrict__ zc)
{
    int bx = blockIdx.x;
    int bkv = bx >> 3, dg = bx & 7;
    int tid = threadIdx.x;
    int d = dg * 16 + (tid & 15);
    int g8 = tid >> 4;                 // e-kgroup 0..15
    float acc[8];
#pragma unroll
    for (int i = 0; i < 8; i++) acc[i] = 0.f;
    float zacc = 0.f;
    for (int c = 0; c < NC_; c++) {
        size_t cb = (size_t)(bkv * NC_ + c);
        const float* p = kvc + cb * 16384;
        float cur[8];
#pragma unroll
        for (int i = 0; i < 8; i++) cur[i] = p[(g8 * 8 + i) * 128 + d];
        uint4 hi, lo;
        pack8(acc, hi, lo);
        char* op = kvct + cb * 65536 + (size_t)d * 512 + g8 * 32;
        *(uint4*)op        = hi;
        *(uint4*)(op + 16) = lo;
#pragma unroll
        for (int i = 0; i < 8; i++) acc[i] += cur[i];
        if (tid < 16) {
            float* zp = zc + cb * 128 + dg * 16 + tid;
            float zcur = *zp;
            *zp = zacc;
            zacc += zcur;
        }
    }
}

// ------------------------------------------------------------------ per-chunk output, MFMA bf16x3
// O = (tril(Q K^T) V + Q Sp) / (rowsum(tril(Q K^T)) + Q zp + eps); packed hi/lo out.
__global__ __launch_bounds__(256, 1) void chunk_out_k(
    const char* __restrict__ qfpk, const char* __restrict__ kfpk,
    const char* __restrict__ vtpk, const char* __restrict__ kvct,
    const float* __restrict__ zc, char* __restrict__ attnpk)
{
    __shared__ __attribute__((aligned(16))) char smem[100864];
    char*  stA  = smem;                       // 16KB staging (A slab)
    char*  stB  = smem + 16384;               // 16KB staging (B slab)
    float* Pf   = (float*)(smem + 32768);     // 64KB [128][128] fp32, 32B-granule XOR swizzle
    float* zs   = (float*)(smem + 98304);     // 128
    float* rsum = (float*)(smem + 98816);     // 128 x 2 (wc partials)
    float* den2 = (float*)(smem + 99840);     // 128
    float* den  = (float*)(smem + 100352);    // 128

    int bx = blockIdx.x;                      // (b*16+h)*16 + c
    int c = bx & 15, h = (bx >> 4) & 15, b = bx >> 8;
    int kv = h >> 2;
    int bkv = b * KVH_ + kv;
    int bkvc = bkv * NC_ + c;
    const char* Qb  = qfpk + ((size_t)(b * H_ + h) * S_ + c * CHK_) * 512;
    const char* Kb  = kfpk + ((size_t)bkv * S_ + c * CHK_) * 512;
    const char* Vtb = vtpk + (size_t)bkv * 1048576 + (size_t)c * 512;   // + d*8192 + s*128
    const char* Spb = kvct + (size_t)bkvc * 65536;                      // + d*512  + s*128
    const float* zp = zc + (size_t)bkvc * 128;

    int tid = threadIdx.x;
    int lane = tid & 63, wv = tid >> 6;
    int wr = wv >> 1, wc = wv & 1;
    int lrow = lane & 15, lg = lane >> 4, l7 = lane & 7;

    if (tid < 32) *(float4*)(zs + tid * 4) = *(const float4*)(zp + tid * 4);

    // staging pointers (gemm3 pattern: 8 rows x 8 swizzled 16B slots per 1KB wave-load)
    const char *qsrc[4], *ksrc[4], *vsrc[4], *ssrc[4];
    char *adst[4], *bdst[4];
#pragma unroll
    for (int i = 0; i < 4; i++) {
        int row = wv * 32 + i * 8 + (lane >> 3);
        int sl = (lane & 7) ^ (row & 7);
        qsrc[i] = Qb  + (size_t)row * 512  + sl * 16;
        ksrc[i] = Kb  + (size_t)row * 512  + sl * 16;
        vsrc[i] = Vtb + (size_t)row * 8192 + sl * 16;
        ssrc[i] = Spb + (size_t)row * 512  + sl * 16;
        adst[i] = stA + wv * 4096 + i * 1024;
        bdst[i] = stB + wv * 4096 + i * 1024;
    }
    int aoffs[4], boffs[4];
#pragma unroll
    for (int f = 0; f < 4; f++) {
        aoffs[f] = (wr * 64 + f * 16 + lrow) * 128 + (((lg << 1) ^ l7) << 4);
        boffs[f] = (wc * 64 + f * 16 + lrow) * 128 + (((lg << 1) ^ l7) << 4);
    }

    // ---------------- GEMM1: S = Q K^T (k = d, 4 slabs) ----------------
    f32x4 acc1[4][4];
#pragma unroll
    for (int i = 0; i < 4; i++)
#pragma unroll
        for (int j = 0; j < 4; j++) acc1[i][j] = (f32x4)(0.f);

    for (int s = 0; s < 4; s++) {
#pragma unroll
        for (int i = 0; i < 4; i++) {
            GLOAD16(qsrc[i] + s * 128, adst[i]);
            GLOAD16(ksrc[i] + s * 128, bdst[i]);
        }
        __syncthreads();
        short8 ah[4], al[4], bh[4], bl[4];
#pragma unroll
        for (int f = 0; f < 4; f++) {
            ah[f] = *(const short8*)(stA + aoffs[f]);
            al[f] = *(const short8*)(stA + (aoffs[f] ^ 16));
            bh[f] = *(const short8*)(stB + boffs[f]);
            bl[f] = *(const short8*)(stB + (boffs[f] ^ 16));
        }
#pragma unroll
        for (int i = 0; i < 4; i++)
#pragma unroll
            for (int j = 0; j < 4; j++) {
                acc1[i][j] = __builtin_amdgcn_mfma_f32_16x16x32_bf16(ah[i], bh[j], acc1[i][j], 0, 0, 0);
                acc1[i][j] = __builtin_amdgcn_mfma_f32_16x16x32_bf16(ah[i], bl[j], acc1[i][j], 0, 0, 0);
                acc1[i][j] = __builtin_amdgcn_mfma_f32_16x16x32_bf16(al[i], bh[j], acc1[i][j], 0, 0, 0);
            }
        __syncthreads();
    }

    // ---------------- mask + rowsum + P -> LDS (swizzled fp32) ----------------
#pragma unroll
    for (int fi = 0; fi < 4; fi++) {
#pragma unroll
        for (int reg = 0; reg < 4; reg++) {
            int i = wr * 64 + fi * 16 + lg * 4 + reg;
            float rsv = 0.f;
#pragma unroll
            for (int fj = 0; fj < 4; fj++) {
                int j = wc * 64 + fj * 16 + lrow;
                float v = (j <= i) ? acc1[fi][fj][reg] : 0.f;
                rsv += v;
                Pf[i * 128 + (((j >> 3) ^ (i & 7)) << 3) + (j & 7)] = v;
            }
#pragma unroll
            for (int m = 1; m < 16; m <<= 1) rsv += __shfl_xor(rsv, m, 64);
            if (lrow == 0) rsum[i * 2 + wc] = rsv;
        }
    }

    // ---------------- GEMM3: O += Q Sp^T (k = e, 4 slabs) + den2 = Q.zp ----------------
    f32x4 acc2[4][4];
#pragma unroll
    for (int i = 0; i < 4; i++)
#pragma unroll
        for (int j = 0; j < 4; j++) acc2[i][j] = (f32x4)(0.f);
    float d2a[4] = {0.f, 0.f, 0.f, 0.f};

    for (int s = 0; s < 4; s++) {
#pragma unroll
        for (int i = 0; i < 4; i++) {
            GLOAD16(qsrc[i] + s * 128, adst[i]);
            GLOAD16(ssrc[i] + s * 128, bdst[i]);
        }
        __syncthreads();
        short8 ah[4], al[4], bh[4], bl[4];
#pragma unroll
        for (int f = 0; f < 4; f++) {
            ah[f] = *(const short8*)(stA + aoffs[f]);
            al[f] = *(const short8*)(stA + (aoffs[f] ^ 16));
            bh[f] = *(const short8*)(stB + boffs[f]);
            bl[f] = *(const short8*)(stB + (boffs[f] ^ 16));
        }
        float zv[8];
#pragma unroll
        for (int e = 0; e < 8; e++) zv[e] = zs[s * 32 + lg * 8 + e];
#pragma unroll
        for (int f = 0; f < 4; f++)
#pragma unroll
            for (int e = 0; e < 8; e++)
                d2a[f] += (bf2f((unsigned int)(unsigned short)ah[f][e]) +
                           bf2f((unsigned int)(unsigned short)al[f][e])) * zv[e];
#pragma unroll
        for (int i = 0; i < 4; i++)
#pragma unroll
            for (int j = 0; j < 4; j++) {
                acc2[i][j] = __builtin_amdgcn_mfma_f32_16x16x32_bf16(ah[i], bh[j], acc2[i][j], 0, 0, 0);
                acc2[i][j] = __builtin_amdgcn_mfma_f32_16x16x32_bf16(ah[i], bl[j], acc2[i][j], 0, 0, 0);
                acc2[i][j] = __builtin_amdgcn_mfma_f32_16x16x32_bf16(al[i], bh[j], acc2[i][j], 0, 0, 0);
            }
        __syncthreads();
    }
#pragma unroll
    for (int f = 0; f < 4; f++) {
        float v = d2a[f];
        v += __shfl_xor(v, 16, 64);
        v += __shfl_xor(v, 32, 64);
        if (wc == 0 && lg == 0) den2[wr * 64 + f * 16 + lrow] = v;
    }

    // ---------------- GEMM2: O += tril(S) V  (k = j, 4 slabs; A from Pf) ----------------
    for (int s = 0; s < 4; s++) {
#pragma unroll
        for (int i = 0; i < 4; i++) GLOAD16(vsrc[i] + s * 128, bdst[i]);
        __syncthreads();
        short8 ph[4], pl[4], bh[4], bl[4];
#pragma unroll
        for (int f = 0; f < 4; f++) {
            int i = wr * 64 + f * 16 + lrow;
            int g = (s * 4 + lg) ^ (i & 7);
            float pv[8];
            *(float4*)&pv[0] = *(const float4*)(Pf + i * 128 + g * 8);
            *(float4*)&pv[4] = *(const float4*)(Pf + i * 128 + g * 8 + 4);
            split8_frag(pv, ph[f], pl[f]);
            bh[f] = *(const short8*)(stB + boffs[f]);
            bl[f] = *(const short8*)(stB + (boffs[f] ^ 16));
        }
#pragma unroll
        for (int i = 0; i < 4; i++)
#pragma unroll
            for (int j = 0; j < 4; j++) {
                acc2[i][j] = __builtin_amdgcn_mfma_f32_16x16x32_bf16(ph[i], bh[j], acc2[i][j], 0, 0, 0);
                acc2[i][j] = __builtin_amdgcn_mfma_f32_16x16x32_bf16(ph[i], bl[j], acc2[i][j], 0, 0, 0);
                acc2[i][j] = __builtin_amdgcn_mfma_f32_16x16x32_bf16(pl[i], bh[j], acc2[i][j], 0, 0, 0);
            }
        __syncthreads();
    }

    // ---------------- epilogue: den combine, divide, repack ----------------
    if (tid < 128) den[tid] = rsum[tid * 2] + rsum[tid * 2 + 1] + den2[tid] + EPS_;
    __syncthreads();
#pragma unroll
    for (int fi = 0; fi < 4; fi++) {
#pragma unroll
        for (int reg = 0; reg < 4; reg++) {
            int i = wr * 64 + fi * 16 + lg * 4 + reg;
            float inv = 1.0f / den[i];
#pragma unroll
            for (int fd = 0; fd < 4; fd++) {
                int d = wc * 64 + fd * 16 + lrow;
                Pf[i * 128 + (((d >> 3) ^ (i & 7)) << 3) + (d & 7)] = acc2[fi][fd][reg] * inv;
            }
        }
    }
    __syncthreads();
    int s0 = c * CHK_;
#pragma unroll
    for (int it = 0; it < 8; it++) {
        int idx = it * 256 + tid;
        int row = idx >> 4, kg = idx & 15;
        int g = kg ^ (row & 7);
        float f[8];
        *(float4*)&f[0] = *(const float4*)(Pf + row * 128 + g * 8);
        *(float4*)&f[4] = *(const float4*)(Pf + row * 128 + g * 8 + 4);
        uint4 hi, lo;
        pack8(f, hi, lo);
        char* op = attnpk + ((size_t)(b * S_ + s0 + row) * 256 + h * 16 + kg) * 32;
        *(uint4*)op        = hi;
        *(uint4*)(op + 16) = lo;
    }
}

// ------------------------------------------------------------------ launch
// ws layout (floats), total 27,541,504 = 110.17 MB (R1/R4-proven footprint):
//   [0,        8388608)  xpk          -> qfpk   (dead after QKV gemm)
//   [8388608, 12582912)  wqpk         -> kfpk [8388608,10485760) | vv [10485760,12582912)
//   [12582912,14680064)  wkpk+wvpk    -> vtpk
//   [14680064,27262976)  qkv fp32     -> kvc [14680064,..) | kvcT [16777216,..) | attnpk [18874368,..)
//                        wopk aliases kvc+kvcT [14680064,18874368), split AFTER chunk_out
//   [27262976,27525120)  cos | sin
//   [27525120,27541504)  zc
extern "C" void kernel_launch(void* const* d_in, const int* in_sizes, int n_in,
                              void* d_out, int out_size, void* d_ws, size_t ws_size,
                              hipStream_t stream)
{
    (void)in_sizes; (void)n_in; (void)out_size; (void)ws_size;
    const float* x  = (const float*)d_in[0];
    const float* Wq = (const float*)d_in[1];
    const float* Wk = (const float*)d_in[2];
    const float* Wv = (const float*)d_in[3];
    const float* Wo = (const float*)d_in[4];
    float* out = (float*)d_out;
    float* ws  = (float*)d_ws;

    float* xpk   = ws;
    float* wqpk  = ws + 8388608;
    float* wkpk  = ws + 12582912;
    float* wvpk  = ws + 13631488;
    float* qkv   = ws + 14680064;
    float* cost  = ws + 27262976;
    float* sint  = ws + 27394048;
    float* zc    = ws + 27525120;

    char*  qfpk   = (char*)xpk;
    char*  kfpk   = (char*)(ws + 8388608);
    float* vv     = ws + 10485760;
    char*  vtpk   = (char*)(ws + 12582912);
    float* kvc    = ws + 14680064;
    char*  kvct   = (char*)(ws + 16777216);
    char*  attnpk = (char*)(ws + 18874368);
    float* wopk   = ws + 14680064;     // over dead kvc+kvcT, split after chunk_out

    rope_tables_k<<<512, 256, 0, stream>>>(cost, sint);

    // phase A: pack inputs, QKV projection (M=4096, N=3072=q|k|v, K=2048)
    split_k<<<4096, 256, 0, stream>>>(x,  (unsigned int*)xpk,  1048576);
    split_k<<<2048, 256, 0, stream>>>(Wq, (unsigned int*)wqpk, 524288);
    split_k<<<512,  256, 0, stream>>>(Wk, (unsigned int*)wkpk, 131072);
    split_k<<<512,  256, 0, stream>>>(Wv, (unsigned int*)wvpk, 131072);
    gemm3_k<<<768, 256, 0, stream>>>((const char*)xpk, (const char*)wqpk,
                                     (const char*)wkpk, (const char*)wvpk,
                                     qkv, 3072, 2048, 2560, 24);

    // phase B: RoPE+feature (packed out), V copy + packed transpose
    rope_feat_k<<<5120, 256, 0, stream>>>(qkv, cost, sint, qfpk, kfpk);
    copy_v_k<<<128, 256, 0, stream>>>(qkv, vv, vtpk);

    // phase C: chunked linear attention (MFMA)
    chunk_kv_k<<<B_ * KVH_ * NC_, 256, 0, stream>>>(kfpk, vv, kvc, zc);
    chunk_scan_k<<<64, 256, 0, stream>>>(kvc, kvct, zc);
    chunk_out_k<<<B_ * H_ * NC_, 256, 0, stream>>>(qfpk, kfpk, vtpk, kvct, zc, attnpk);

    // phase D: pack Wo (kvc/kvcT now dead), O projection (M=4096, N=2048, K=2048)
    split_k<<<2048, 256, 0, stream>>>(Wo, (unsigned int*)wopk, 524288);
    gemm3_k<<<512, 256, 0, stream>>>((const char*)attnpk, (const char*)wopk,
                                     (const char*)wopk, (const char*)wopk,
                                     out, 2048, 1 << 30, 1 << 30, 16);
}

// Round 6
// 426.619 us; speedup vs baseline: 3.0344x; 1.0760x over previous
//
#include <hip/hip_runtime.h>
#include <math.h>
#include <stdint.h>

#define B_ 2
#define S_ 2048
#define H_ 16
#define KVH_ 4
#define HD_ 128
#define NC_ 16
#define CHK_ 128
#define EPS_ 1e-6f
#define GK_ 2048          // K dim of both big GEMMs
#define NT_ (GK_ / 32)    // K-tiles of 32

typedef __attribute__((ext_vector_type(8))) short short8;   // 8 bf16 (4 VGPR)
typedef __attribute__((ext_vector_type(4))) float f32x4;

// async global->LDS, 16B per lane; LDS dst wave-uniform base + lane*16
#define GLOAD16(gsrc, sdst) \
    __builtin_amdgcn_global_load_lds((const __attribute__((address_space(1))) unsigned int*)(gsrc), \
                                     (__attribute__((address_space(3))) unsigned int*)(sdst), 16, 0, 0)

static __device__ __forceinline__ float bf2f(unsigned int u) {
    return __uint_as_float(u << 16);
}

// 8 fp32 -> hi/lo bf16 uint4 pair (truncation split, residual exact)
static __device__ __forceinline__ void pack8(const float* v, uint4& hi, uint4& lo) {
    unsigned int h[4], l[4];
#pragma unroll
    for (int w = 0; w < 4; w++) {
        unsigned int b0 = __float_as_uint(v[2 * w]);
        unsigned int b1 = __float_as_uint(v[2 * w + 1]);
        unsigned int h0 = b0 & 0xFFFF0000u, h1 = b1 & 0xFFFF0000u;
        h[w] = (h0 >> 16) | h1;
        float r0 = v[2 * w] - __uint_as_float(h0);
        float r1 = v[2 * w + 1] - __uint_as_float(h1);
        l[w] = (__float_as_uint(r0) >> 16) | (__float_as_uint(r1) & 0xFFFF0000u);
    }
    hi = make_uint4(h[0], h[1], h[2], h[3]);
    lo = make_uint4(l[0], l[1], l[2], l[3]);
}

// 8 fp32 -> hi/lo short8 MFMA fragments
static __device__ __forceinline__ void split8_frag(const float* p, short8& hi, short8& lo) {
#pragma unroll
    for (int e = 0; e < 8; e++) {
        unsigned int b = __float_as_uint(p[e]);
        unsigned int h = b & 0xFFFF0000u;
        hi[e] = (short)(h >> 16);
        float r = p[e] - __uint_as_float(h);
        lo[e] = (short)(__float_as_uint(r) >> 16);
    }
}

// ------------------------------------------------------------------ RoPE tables
__global__ __launch_bounds__(256) void rope_tables_k(float* __restrict__ cost,
                                                     float* __restrict__ sint) {
    int idx = blockIdx.x * 256 + threadIdx.x;      // S_*64 exact
    int j = idx & 63;
    int s = idx >> 6;
    float inv_freq = powf(10000.0f, -(float)(2 * j) / 128.0f);
    float f = (float)s * inv_freq;
    cost[idx] = cosf(f);
    sint[idx] = sinf(f);
}

// ------------------------------------------------------------------ fused input packer
// x (1,048,576 grp) | Wq (524,288) | Wk (131,072) | Wv (131,072) -> 7168 blocks exact
__global__ __launch_bounds__(256) void split_in_k(
    const float* __restrict__ x,  const float* __restrict__ wq,
    const float* __restrict__ wk, const float* __restrict__ wv,
    unsigned int* __restrict__ xpk,  unsigned int* __restrict__ wqpk,
    unsigned int* __restrict__ wkpk, unsigned int* __restrict__ wvpk)
{
    int g = blockIdx.x * 256 + threadIdx.x;
    const float* in;
    unsigned int* outp;
    int lg;
    if (g < 1048576)      { in = x;  outp = xpk;  lg = g; }
    else if (g < 1572864) { in = wq; outp = wqpk; lg = g - 1048576; }
    else if (g < 1703936) { in = wk; outp = wkpk; lg = g - 1572864; }
    else                  { in = wv; outp = wvpk; lg = g - 1703936; }
    const float* p = in + (size_t)lg * 8;
    float v[8];
    *(float4*)&v[0] = *(const float4*)p;
    *(float4*)&v[4] = *(const float4*)(p + 4);
    uint4 hi, lo;
    pack8(v, hi, lo);
    unsigned int* op = outp + (size_t)lg * 8;
    *(uint4*)op       = hi;
    *(uint4*)(op + 4) = lo;
}

// ------------------------------------------------------------------ plain packer (Wo)
__global__ __launch_bounds__(256) void split_k(const float* __restrict__ in,
                                               unsigned int* __restrict__ outp, int ngrp)
{
    int g = blockIdx.x * 256 + threadIdx.x;
    if (g >= ngrp) return;
    const float* p = in + (size_t)g * 8;
    float x[8];
    *(float4*)&x[0] = *(const float4*)p;
    *(float4*)&x[4] = *(const float4*)(p + 4);
    uint4 hi, lo;
    pack8(x, hi, lo);
    unsigned int* op = outp + (size_t)g * 8;
    *(uint4*)op       = hi;
    *(uint4*)(op + 4) = lo;
}

// ------------------------------------------------------------------ bf16x3 MFMA GEMM
// Y[m,n] = sum_k A[m,k] W[n,k], packed hi/lo inputs (rowbytes = K*4).
// EPI=0: fp32 store to Y. EPI=1: fused QKV epilogue — RoPE+elu+pack for q/k heads
// (n-tile == one head since HD=128), fp32 row store to vv for v heads.
template <int EPI>
__global__ __launch_bounds__(256, 2) void gemm3_k(
    const char* __restrict__ Apk, const char* __restrict__ W0,
    const char* __restrict__ W1, const char* __restrict__ W2,
    float* __restrict__ Y, int ldY, int nend0, int nend1, int nbx,
    const float* __restrict__ cosT, const float* __restrict__ sinT,
    char* __restrict__ qfo, char* __restrict__ kfo, float* __restrict__ vvo)
{
    __shared__ __attribute__((aligned(16))) char smem[65536];

    int nwg = gridDim.x;
    int bid = blockIdx.x;
    int swz = (bid & 7) * (nwg >> 3) + (bid >> 3);
    int by = swz / nbx, bx = swz % nbx;
    const int m0 = by * 128, n0 = bx * 128;

    const char* Wsel;
    int nw;
    if (n0 < nend0)      { Wsel = W0; nw = n0; }
    else if (n0 < nend1) { Wsel = W1; nw = n0 - nend0; }
    else                 { Wsel = W2; nw = n0 - nend1; }

    const int tid = threadIdx.x;
    const int lane = tid & 63;
    const int wv = tid >> 6;
    const int wr = wv >> 1, wc = wv & 1;

    const int r8 = lane >> 3, sl = lane & 7;
    const char* ap[4];
    const char* wp[4];
    int adst[4], wdst[4];
#pragma unroll
    for (int i = 0; i < 4; i++) {
        int rowA = wv * 32 + i * 8 + r8;
        ap[i] = Apk + (size_t)(m0 + rowA) * (GK_ * 4) + (size_t)((sl ^ (rowA & 7)) * 16);
        wp[i] = Wsel + (size_t)(nw + rowA) * (GK_ * 4) + (size_t)((sl ^ (rowA & 7)) * 16);
        adst[i] = wv * 4096 + i * 1024;
        wdst[i] = 16384 + wv * 4096 + i * 1024;
    }

    const int lrow = lane & 15, lg = lane >> 4, lc7 = lane & 7;
    const int aoff = (wr * 64 + lrow) * 128 + ((((lg << 1)) ^ lc7) << 4);
    const int woff = 16384 + (wc * 64 + lrow) * 128 + ((((lg << 1)) ^ lc7) << 4);

    f32x4 acc[4][4];
#pragma unroll
    for (int i = 0; i < 4; i++)
#pragma unroll
        for (int j = 0; j < 4; j++) acc[i][j] = (f32x4)(0.f);

#pragma unroll
    for (int i = 0; i < 4; i++) {
        GLOAD16(ap[i], smem + adst[i]);
        GLOAD16(wp[i], smem + wdst[i]);
    }
    __syncthreads();

    for (int kt = 0; kt < NT_; ++kt) {
        const int cur = kt & 1;
        if (kt + 1 < NT_) {
            const size_t koff = (size_t)(kt + 1) * 128;
            const int nb = (cur ^ 1) * 32768;
#pragma unroll
            for (int i = 0; i < 4; i++) {
                GLOAD16(ap[i] + koff, smem + nb + adst[i]);
                GLOAD16(wp[i] + koff, smem + nb + wdst[i]);
            }
        }
        const char* sb = smem + cur * 32768;
        short8 ah[4], al[4], bh[4], bl[4];
#pragma unroll
        for (int f = 0; f < 4; f++) {
            ah[f] = *(const short8*)(sb + (aoff)        + f * 2048);
            al[f] = *(const short8*)(sb + (aoff ^ 16)   + f * 2048);
            bh[f] = *(const short8*)(sb + (woff)        + f * 2048);
            bl[f] = *(const short8*)(sb + (woff ^ 16)   + f * 2048);
        }
#pragma unroll
        for (int i = 0; i < 4; i++)
#pragma unroll
            for (int j = 0; j < 4; j++) {
                acc[i][j] = __builtin_amdgcn_mfma_f32_16x16x32_bf16(ah[i], bh[j], acc[i][j], 0, 0, 0);
                acc[i][j] = __builtin_amdgcn_mfma_f32_16x16x32_bf16(ah[i], bl[j], acc[i][j], 0, 0, 0);
                acc[i][j] = __builtin_amdgcn_mfma_f32_16x16x32_bf16(al[i], bh[j], acc[i][j], 0, 0, 0);
            }
        __syncthreads();
    }

    if (EPI == 0) {
        // plain fp32 store; C/D layout col = lane&15, row = (lane>>4)*4 + reg
#pragma unroll
        for (int i = 0; i < 4; i++) {
            int r0 = m0 + wr * 64 + i * 16 + lg * 4;
#pragma unroll
            for (int j = 0; j < 4; j++) {
                int cc = n0 + wc * 64 + j * 16 + lrow;
                f32x4 v = acc[i][j];
                Y[(size_t)(r0 + 0) * ldY + cc] = v[0];
                Y[(size_t)(r0 + 1) * ldY + cc] = v[1];
                Y[(size_t)(r0 + 2) * ldY + cc] = v[2];
                Y[(size_t)(r0 + 3) * ldY + cc] = v[3];
            }
        }
    } else {
        // fused QKV epilogue: C tile -> LDS (staging dead after final barrier)
        float* Ct = (float*)smem;      // [128][128] fp32 = 64KB
#pragma unroll
        for (int i = 0; i < 4; i++) {
            int r = wr * 64 + i * 16 + lg * 4;
#pragma unroll
            for (int j = 0; j < 4; j++) {
                int ccol = wc * 64 + j * 16 + lrow;
#pragma unroll
                for (int rr = 0; rr < 4; rr++)
                    Ct[(r + rr) * 128 + ccol] = acc[i][j][rr];
            }
        }
        __syncthreads();
        if (n0 < 2560) {
            // q or k head: RoPE + elu(+1) + pack hi/lo
            const int isq = (n0 < 2048) ? 1 : 0;
            const int hh = isq ? (n0 >> 7) : ((n0 - 2048) >> 7);
            char* basep = isq ? qfo : kfo;
            const int bstride = (isq ? H_ : KVH_) * S_;
#pragma unroll
            for (int it = 0; it < 8; it++) {
                int idx = it * 256 + tid;
                int row = idx >> 4, g = idx & 15;
                int midx = m0 + row, bb = midx >> 11, ss = midx & 2047;
                int j0 = g * 8;
                int lowh = (j0 < 64) ? 1 : 0;
                int f0 = lowh ? j0 : j0 - 64;
                float o[8];
#pragma unroll
                for (int e = 0; e < 8; e++) {
                    float cs = cosT[ss * 64 + f0 + e];
                    float sn = sinT[ss * 64 + f0 + e];
                    float a = Ct[row * 128 + j0 + e];
                    float p = Ct[row * 128 + (lowh ? j0 + e + 64 : j0 + e - 64)];
                    float v = lowh ? (a * cs - p * sn) : (a * cs + p * sn);
                    o[e] = v > 0.f ? v + 1.f : expf(v);
                }
                uint4 hi, lo;
                pack8(o, hi, lo);
                char* dst = basep + ((size_t)bb * bstride + (size_t)hh * S_ + ss) * 512 + g * 32;
                *(uint4*)dst        = hi;
                *(uint4*)(dst + 16) = lo;
            }
        } else {
            // v head: fp32 rows to vv
            const int kvh = (n0 - 2560) >> 7;
#pragma unroll
            for (int it = 0; it < 16; it++) {
                int idx = it * 256 + tid;
                int r = idx >> 5, c4 = idx & 31;
                int midx = m0 + r, bb = midx >> 11, ss = midx & 2047;
                *(float4*)(vvo + ((size_t)(bb * KVH_ + kvh) * S_ + ss) * HD_ + c4 * 4) =
                    *(const float4*)(Ct + r * 128 + c4 * 4);
            }
        }
    }
}

// ------------------------------------------------------------------ vv -> packed V^T
// vtpk layout: [bkv][d=128 rows][S/8=256 kgroups x 32B], row stride 8192B.
__global__ __launch_bounds__(256) void vt_k(const float* __restrict__ vv,
                                            char* __restrict__ vtpk)
{
    __shared__ __attribute__((aligned(16))) float Vt[CHK_][HD_ + 4];
    int bx = blockIdx.x;               // bkv*16 + st
    int st = bx & 15;
    int bkv = bx >> 4;
    int tid = threadIdx.x;
#pragma unroll
    for (int it = 0; it < 16; it++) {
        int idx = it * 256 + tid;
        int r = idx >> 5, c4 = idx & 31;
        *(float4*)&Vt[r][c4 * 4] =
            *(const float4*)(vv + ((size_t)bkv * S_ + st * CHK_ + r) * HD_ + c4 * 4);
    }
    __syncthreads();
#pragma unroll
    for (int it = 0; it < 2; it++) {
        int t2 = it * 256 + tid;       // 0..511
        int d = t2 & 127, sg = t2 >> 7;
#pragma unroll
        for (int kk = 0; kk < 4; kk++) {
            int kgl = sg * 4 + kk;
            float f[8];
#pragma unroll
            for (int e = 0; e < 8; e++) f[e] = Vt[kgl * 8 + e][d];
            uint4 hi, lo;
            pack8(f, hi, lo);
            char* op = vtpk + (size_t)bkv * 1048576 + (size_t)d * 8192 + (size_t)(st * 16 + kgl) * 32;
            *(uint4*)op        = hi;
            *(uint4*)(op + 16) = lo;
        }
    }
}

// ------------------------------------------------------------------ per-chunk KV summaries (K from packed)
__global__ __launch_bounds__(256) void chunk_kv_k(
    const char* __restrict__ kfpk, const float* __restrict__ vv,
    float* __restrict__ kvc, float* __restrict__ zc)
{
    int bx = blockIdx.x;
    int c = bx % NC_;
    int bkv = bx / NC_;
    const char* kp = kfpk + ((size_t)bkv * S_ + c * CHK_) * 512;
    const float* vp = vv + ((size_t)bkv * S_ + c * CHK_) * HD_;
    __shared__ __attribute__((aligned(16))) float ks[CHK_][HD_ + 4];
    __shared__ __attribute__((aligned(16))) float vs[CHK_][HD_ + 4];
    int tid = threadIdx.x, tx = tid & 15, ty = tid >> 4;
#pragma unroll
    for (int it = 0; it < 8; it++) {       // 128 rows x 16 kgroups
        int idx = it * 256 + tid;
        int r = idx >> 4, kg = idx & 15;
        const uint4* sp = (const uint4*)(kp + (size_t)r * 512 + kg * 32);
        uint4 hi = sp[0], lo = sp[1];
        float* d = &ks[r][kg * 8];
        d[0] = bf2f(hi.x & 0xFFFFu) + bf2f(lo.x & 0xFFFFu);
        d[1] = bf2f(hi.x >> 16)     + bf2f(lo.x >> 16);
        d[2] = bf2f(hi.y & 0xFFFFu) + bf2f(lo.y & 0xFFFFu);
        d[3] = bf2f(hi.y >> 16)     + bf2f(lo.y >> 16);
        d[4] = bf2f(hi.z & 0xFFFFu) + bf2f(lo.z & 0xFFFFu);
        d[5] = bf2f(hi.z >> 16)     + bf2f(lo.z >> 16);
        d[6] = bf2f(hi.w & 0xFFFFu) + bf2f(lo.w & 0xFFFFu);
        d[7] = bf2f(hi.w >> 16)     + bf2f(lo.w >> 16);
    }
#pragma unroll
    for (int it = 0; it < 16; it++) {
        int idx = it * 256 + tid;
        int r = idx >> 5, c4 = idx & 31;
        *(float4*)&vs[r][c4 * 4] = *(const float4*)(vp + (size_t)r * HD_ + c4 * 4);
    }
    __syncthreads();
    float acc[8][8];
#pragma unroll
    for (int i = 0; i < 8; i++)
#pragma unroll
        for (int j = 0; j < 8; j++) acc[i][j] = 0.f;
    for (int j = 0; j < CHK_; j++) {
        float a[8], b[8];
        *(float4*)&a[0] = *(const float4*)&ks[j][ty * 8];
        *(float4*)&a[4] = *(const float4*)&ks[j][ty * 8 + 4];
        *(float4*)&b[0] = *(const float4*)&vs[j][tx * 8];
        *(float4*)&b[4] = *(const float4*)&vs[j][tx * 8 + 4];
#pragma unroll
        for (int i = 0; i < 8; i++)
#pragma unroll
            for (int jj = 0; jj < 8; jj++)
                acc[i][jj] = fmaf(a[i], b[jj], acc[i][jj]);
    }
    float* outp = kvc + (size_t)bx * (HD_ * HD_);
#pragma unroll
    for (int i = 0; i < 8; i++) {
        float* op = outp + (size_t)(ty * 8 + i) * HD_ + tx * 8;
        *(float4*)op       = make_float4(acc[i][0], acc[i][1], acc[i][2], acc[i][3]);
        *(float4*)(op + 4) = make_float4(acc[i][4], acc[i][5], acc[i][6], acc[i][7]);
    }
    if (tid < CHK_) {
        float z = 0.f;
        for (int j = 0; j < CHK_; j++) z += ks[j][tid];
        zc[(size_t)bx * HD_ + tid] = z;
    }
}

// ------------------------------------------------------------------ exclusive chunk scan
// 64 blocks (bkv x dgroup). Emits packed-transposed exclusive prefix
// kvcT[bkvc][d=128 rows][16 e-kgroups x 32B]; zc prefix in place (fp32).
__global__ __launch_bounds__(256) void chunk_scan_k(const float* __restrict__ kvc,
                                                    char* __restrict__ kvct,
                                                    float* __restrict__ zc)
{
    int bx = blockIdx.x;
    int bkv = bx >> 3, dg = bx & 7;
    int tid = threadIdx.x;
    int d = dg * 16 + (tid & 15);
    int g8 = tid >> 4;                 // e-kgroup 0..15
    float acc[8];
#pragma unroll
    for (int i = 0; i < 8; i++) acc[i] = 0.f;
    float zacc = 0.f;
    for (int c = 0; c < NC_; c++) {
        size_t cb = (size_t)(bkv * NC_ + c);
        const float* p = kvc + cb * 16384;
        float cur[8];
#pragma unroll
        for (int i = 0; i < 8; i++) cur[i] = p[(g8 * 8 + i) * 128 + d];
        uint4 hi, lo;
        pack8(acc, hi, lo);
        char* op = kvct + cb * 65536 + (size_t)d * 512 + g8 * 32;
        *(uint4*)op        = hi;
        *(uint4*)(op + 16) = lo;
#pragma unroll
        for (int i = 0; i < 8; i++) acc[i] += cur[i];
        if (tid < 16) {
            float* zp = zc + cb * 128 + dg * 16 + tid;
            float zcur = *zp;
            *zp = zacc;
            zacc += zcur;
        }
    }
}

// ------------------------------------------------------------------ per-chunk output, MFMA bf16x3
// O = (tril(Q K^T) V + Q Sp) / (rowsum(tril(Q K^T)) + Q zp + eps); packed hi/lo out.
__global__ __launch_bounds__(256, 1) void chunk_out_k(
    const char* __restrict__ qfpk, const char* __restrict__ kfpk,
    const char* __restrict__ vtpk, const char* __restrict__ kvct,
    const float* __restrict__ zc, char* __restrict__ attnpk)
{
    __shared__ __attribute__((aligned(16))) char smem[100864];
    char*  stA  = smem;                       // 16KB staging (A slab)
    char*  stB  = smem + 16384;               // 16KB staging (B slab)
    float* Pf   = (float*)(smem + 32768);     // 64KB [128][128] fp32, 32B-granule XOR swizzle
    float* zs   = (float*)(smem + 98304);     // 128
    float* rsum = (float*)(smem + 98816);     // 128 x 2 (wc partials)
    float* den2 = (float*)(smem + 99840);     // 128
    float* den  = (float*)(smem + 100352);    // 128

    int bx = blockIdx.x;                      // (b*16+h)*16 + c
    int c = bx & 15, h = (bx >> 4) & 15, b = bx >> 8;
    int kv = h >> 2;
    int bkv = b * KVH_ + kv;
    int bkvc = bkv * NC_ + c;
    const char* Qb  = qfpk + ((size_t)(b * H_ + h) * S_ + c * CHK_) * 512;
    const char* Kb  = kfpk + ((size_t)bkv * S_ + c * CHK_) * 512;
    const char* Vtb = vtpk + (size_t)bkv * 1048576 + (size_t)c * 512;   // + d*8192 + s*128
    const char* Spb = kvct + (size_t)bkvc * 65536;                      // + d*512  + s*128
    const float* zp = zc + (size_t)bkvc * 128;

    int tid = threadIdx.x;
    int lane = tid & 63, wv = tid >> 6;
    int wr = wv >> 1, wc = wv & 1;
    int lrow = lane & 15, lg = lane >> 4, l7 = lane & 7;

    if (tid < 32) *(float4*)(zs + tid * 4) = *(const float4*)(zp + tid * 4);

    const char *qsrc[4], *ksrc[4], *vsrc[4], *ssrc[4];
    char *adst[4], *bdst[4];
#pragma unroll
    for (int i = 0; i < 4; i++) {
        int row = wv * 32 + i * 8 + (lane >> 3);
        int sl = (lane & 7) ^ (row & 7);
        qsrc[i] = Qb  + (size_t)row * 512  + sl * 16;
        ksrc[i] = Kb  + (size_t)row * 512  + sl * 16;
        vsrc[i] = Vtb + (size_t)row * 8192 + sl * 16;
        ssrc[i] = Spb + (size_t)row * 512  + sl * 16;
        adst[i] = stA + wv * 4096 + i * 1024;
        bdst[i] = stB + wv * 4096 + i * 1024;
    }
    int aoffs[4], boffs[4];
#pragma unroll
    for (int f = 0; f < 4; f++) {
        aoffs[f] = (wr * 64 + f * 16 + lrow) * 128 + (((lg << 1) ^ l7) << 4);
        boffs[f] = (wc * 64 + f * 16 + lrow) * 128 + (((lg << 1) ^ l7) << 4);
    }

    // ---------------- GEMM1: S = Q K^T ----------------
    f32x4 acc1[4][4];
#pragma unroll
    for (int i = 0; i < 4; i++)
#pragma unroll
        for (int j = 0; j < 4; j++) acc1[i][j] = (f32x4)(0.f);

    for (int s = 0; s < 4; s++) {
#pragma unroll
        for (int i = 0; i < 4; i++) {
            GLOAD16(qsrc[i] + s * 128, adst[i]);
            GLOAD16(ksrc[i] + s * 128, bdst[i]);
        }
        __syncthreads();
        short8 ah[4], al[4], bh[4], bl[4];
#pragma unroll
        for (int f = 0; f < 4; f++) {
            ah[f] = *(const short8*)(stA + aoffs[f]);
            al[f] = *(const short8*)(stA + (aoffs[f] ^ 16));
            bh[f] = *(const short8*)(stB + boffs[f]);
            bl[f] = *(const short8*)(stB + (boffs[f] ^ 16));
        }
#pragma unroll
        for (int i = 0; i < 4; i++)
#pragma unroll
            for (int j = 0; j < 4; j++) {
                acc1[i][j] = __builtin_amdgcn_mfma_f32_16x16x32_bf16(ah[i], bh[j], acc1[i][j], 0, 0, 0);
                acc1[i][j] = __builtin_amdgcn_mfma_f32_16x16x32_bf16(ah[i], bl[j], acc1[i][j], 0, 0, 0);
                acc1[i][j] = __builtin_amdgcn_mfma_f32_16x16x32_bf16(al[i], bh[j], acc1[i][j], 0, 0, 0);
            }
        __syncthreads();
    }

    // ---------------- mask + rowsum + P -> LDS ----------------
#pragma unroll
    for (int fi = 0; fi < 4; fi++) {
#pragma unroll
        for (int reg = 0; reg < 4; reg++) {
            int i = wr * 64 + fi * 16 + lg * 4 + reg;
            float rsv = 0.f;
#pragma unroll
            for (int fj = 0; fj < 4; fj++) {
                int j = wc * 64 + fj * 16 + lrow;
                float v = (j <= i) ? acc1[fi][fj][reg] : 0.f;
                rsv += v;
                Pf[i * 128 + (((j >> 3) ^ (i & 7)) << 3) + (j & 7)] = v;
            }
#pragma unroll
            for (int m = 1; m < 16; m <<= 1) rsv += __shfl_xor(rsv, m, 64);
            if (lrow == 0) rsum[i * 2 + wc] = rsv;
        }
    }

    // ---------------- GEMM3: O += Q Sp^T + den2 = Q.zp ----------------
    f32x4 acc2[4][4];
#pragma unroll
    for (int i = 0; i < 4; i++)
#pragma unroll
        for (int j = 0; j < 4; j++) acc2[i][j] = (f32x4)(0.f);
    float d2a[4] = {0.f, 0.f, 0.f, 0.f};

    for (int s = 0; s < 4; s++) {
#pragma unroll
        for (int i = 0; i < 4; i++) {
            GLOAD16(qsrc[i] + s * 128, adst[i]);
            GLOAD16(ssrc[i] + s * 128, bdst[i]);
        }
        __syncthreads();
        short8 ah[4], al[4], bh[4], bl[4];
#pragma unroll
        for (int f = 0; f < 4; f++) {
            ah[f] = *(const short8*)(stA + aoffs[f]);
            al[f] = *(const short8*)(stA + (aoffs[f] ^ 16));
            bh[f] = *(const short8*)(stB + boffs[f]);
            bl[f] = *(const short8*)(stB + (boffs[f] ^ 16));
        }
        float zv[8];
#pragma unroll
        for (int e = 0; e < 8; e++) zv[e] = zs[s * 32 + lg * 8 + e];
#pragma unroll
        for (int f = 0; f < 4; f++)
#pragma unroll
            for (int e = 0; e < 8; e++)
                d2a[f] += (bf2f((unsigned int)(unsigned short)ah[f][e]) +
                           bf2f((unsigned int)(unsigned short)al[f][e])) * zv[e];
#pragma unroll
        for (int i = 0; i < 4; i++)
#pragma unroll
            for (int j = 0; j < 4; j++) {
                acc2[i][j] = __builtin_amdgcn_mfma_f32_16x16x32_bf16(ah[i], bh[j], acc2[i][j], 0, 0, 0);
                acc2[i][j] = __builtin_amdgcn_mfma_f32_16x16x32_bf16(ah[i], bl[j], acc2[i][j], 0, 0, 0);
                acc2[i][j] = __builtin_amdgcn_mfma_f32_16x16x32_bf16(al[i], bh[j], acc2[i][j], 0, 0, 0);
            }
        __syncthreads();
    }
#pragma unroll
    for (int f = 0; f < 4; f++) {
        float v = d2a[f];
        v += __shfl_xor(v, 16, 64);
        v += __shfl_xor(v, 32, 64);
        if (wc == 0 && lg == 0) den2[wr * 64 + f * 16 + lrow] = v;
    }

    // ---------------- GEMM2: O += tril(S) V ----------------
    for (int s = 0; s < 4; s++) {
#pragma unroll
        for (int i = 0; i < 4; i++) GLOAD16(vsrc[i] + s * 128, bdst[i]);
        __syncthreads();
        short8 ph[4], pl[4], bh[4], bl[4];
#pragma unroll
        for (int f = 0; f < 4; f++) {
            int i = wr * 64 + f * 16 + lrow;
            int g = (s * 4 + lg) ^ (i & 7);
            float pv[8];
            *(float4*)&pv[0] = *(const float4*)(Pf + i * 128 + g * 8);
            *(float4*)&pv[4] = *(const float4*)(Pf + i * 128 + g * 8 + 4);
            split8_frag(pv, ph[f], pl[f]);
            bh[f] = *(const short8*)(stB + boffs[f]);
            bl[f] = *(const short8*)(stB + (boffs[f] ^ 16));
        }
#pragma unroll
        for (int i = 0; i < 4; i++)
#pragma unroll
            for (int j = 0; j < 4; j++) {
                acc2[i][j] = __builtin_amdgcn_mfma_f32_16x16x32_bf16(ph[i], bh[j], acc2[i][j], 0, 0, 0);
                acc2[i][j] = __builtin_amdgcn_mfma_f32_16x16x32_bf16(ph[i], bl[j], acc2[i][j], 0, 0, 0);
                acc2[i][j] = __builtin_amdgcn_mfma_f32_16x16x32_bf16(pl[i], bh[j], acc2[i][j], 0, 0, 0);
            }
        __syncthreads();
    }

    // ---------------- epilogue: den combine, divide, repack ----------------
    if (tid < 128) den[tid] = rsum[tid * 2] + rsum[tid * 2 + 1] + den2[tid] + EPS_;
    __syncthreads();
#pragma unroll
    for (int fi = 0; fi < 4; fi++) {
#pragma unroll
        for (int reg = 0; reg < 4; reg++) {
            int i = wr * 64 + fi * 16 + lg * 4 + reg;
            float inv = 1.0f / den[i];
#pragma unroll
            for (int fd = 0; fd < 4; fd++) {
                int d = wc * 64 + fd * 16 + lrow;
                Pf[i * 128 + (((d >> 3) ^ (i & 7)) << 3) + (d & 7)] = acc2[fi][fd][reg] * inv;
            }
        }
    }
    __syncthreads();
    int s0 = c * CHK_;
#pragma unroll
    for (int it = 0; it < 8; it++) {
        int idx = it * 256 + tid;
        int row = idx >> 4, kg = idx & 15;
        int g = kg ^ (row & 7);
        float f[8];
        *(float4*)&f[0] = *(const float4*)(Pf + row * 128 + g * 8);
        *(float4*)&f[4] = *(const float4*)(Pf + row * 128 + g * 8 + 4);
        uint4 hi, lo;
        pack8(f, hi, lo);
        char* op = attnpk + ((size_t)(b * S_ + s0 + row) * 256 + h * 16 + kg) * 32;
        *(uint4*)op        = hi;
        *(uint4*)(op + 16) = lo;
    }
}

// ------------------------------------------------------------------ launch
// ws layout (floats), total 27,541,504 = 110.17 MB (proven footprint), lifetime-aliased:
//   [0,        8388608)  xpk        -> attnpk (xpk dead after gemm<1>)
//   [8388608, 12582912)  wqpk       -> vtpk [8388608,10485760) + kvc [10485760,12582912)
//                                   -> wopk [8388608,12582912) after chunk_out
//   [12582912,14680064)  wkpk+wvpk  -> kvct
//   [14680064,23068672)  qfpk
//   [23068672,25165824)  kfpk
//   [25165824,27262976)  vv
//   [27262976,27525120)  cos | sin
//   [27525120,27541504)  zc
extern "C" void kernel_launch(void* const* d_in, const int* in_sizes, int n_in,
                              void* d_out, int out_size, void* d_ws, size_t ws_size,
                              hipStream_t stream)
{
    (void)in_sizes; (void)n_in; (void)out_size; (void)ws_size;
    const float* x  = (const float*)d_in[0];
    const float* Wq = (const float*)d_in[1];
    const float* Wk = (const float*)d_in[2];
    const float* Wv = (const float*)d_in[3];
    const float* Wo = (const float*)d_in[4];
    float* out = (float*)d_out;
    float* ws  = (float*)d_ws;

    float* xpk   = ws;
    float* wqpk  = ws + 8388608;
    float* wkpk  = ws + 12582912;
    float* wvpk  = ws + 13631488;
    char*  qfpk  = (char*)(ws + 14680064);
    char*  kfpk  = (char*)(ws + 23068672);
    float* vv    = ws + 25165824;
    float* cost  = ws + 27262976;
    float* sint  = ws + 27394048;
    float* zc    = ws + 27525120;
    // post-gemm aliases
    char*  vtpk   = (char*)(ws + 8388608);
    float* kvc    = ws + 10485760;
    char*  kvct   = (char*)(ws + 12582912);
    char*  attnpk = (char*)ws;
    float* wopk   = ws + 8388608;      // over dead vtpk+kvc, split after chunk_out

    rope_tables_k<<<512, 256, 0, stream>>>(cost, sint);

    // phase A: pack x|Wq|Wk|Wv (one launch), fused QKV GEMM (M=4096, N=3072, K=2048)
    split_in_k<<<7168, 256, 0, stream>>>(x, Wq, Wk, Wv,
                                         (unsigned int*)xpk, (unsigned int*)wqpk,
                                         (unsigned int*)wkpk, (unsigned int*)wvpk);
    gemm3_k<1><<<768, 256, 0, stream>>>((const char*)xpk, (const char*)wqpk,
                                        (const char*)wkpk, (const char*)wvpk,
                                        nullptr, 0, 2048, 2560, 24,
                                        cost, sint, qfpk, kfpk, vv);

    // phase B: packed V^T from vv
    vt_k<<<128, 256, 0, stream>>>(vv, vtpk);

    // phase C: chunked linear attention (MFMA)
    chunk_kv_k<<<B_ * KVH_ * NC_, 256, 0, stream>>>(kfpk, vv, kvc, zc);
    chunk_scan_k<<<64, 256, 0, stream>>>(kvc, kvct, zc);
    chunk_out_k<<<B_ * H_ * NC_, 256, 0, stream>>>(qfpk, kfpk, vtpk, kvct, zc, attnpk);

    // phase D: pack Wo (vtpk/kvc now dead), O projection (M=4096, N=2048, K=2048)
    split_k<<<2048, 256, 0, stream>>>(Wo, (unsigned int*)wopk, 524288);
    gemm3_k<0><<<512, 256, 0, stream>>>((const char*)attnpk, (const char*)wopk,
                                        (const char*)wopk, (const char*)wopk,
                                        out, 2048, 1 << 30, 1 << 30, 16,
                                        nullptr, nullptr, nullptr, nullptr, nullptr);
}